// Round 2
// baseline (15838.095 us; speedup 1.0000x reference)
//
#include <hip/hip_runtime.h>
#include <hip/hip_bf16.h>

#define B_    2
#define S_    2048
#define D_    1024
#define H_    16
#define DH_   64
#define DR_   64
#define DL_   512
#define DHID_ 512
#define T_    (B_*S_)

// ---------------- rmsnorm (f32 input) ----------------
__global__ __launch_bounds__(256) void rmsnorm_kernel(const float* __restrict__ x,
    const float* __restrict__ w, float* __restrict__ out)
{
    int t = blockIdx.x, tid = threadIdx.x;
    const float* xp = x + (size_t)t * D_;
    __shared__ float red[256];
    float s = 0.f;
    for (int d = tid; d < D_; d += 256) { float v = xp[d]; s += v * v; }
    red[tid] = s; __syncthreads();
    for (int o = 128; o > 0; o >>= 1) { if (tid < o) red[tid] += red[tid + o]; __syncthreads(); }
    float inv = rsqrtf(red[0] * (1.f / D_) + 1e-6f);
    float* op = out + (size_t)t * D_;
    for (int d = tid; d < D_; d += 256) op[d] = xp[d] * inv * w[d];
}

// ---------------- tiled GEMM: C(M,N) = A(M,K) * B(K,N), all f32 ----------------
#define BM 64
#define BN 64
#define BK 16
__global__ __launch_bounds__(256) void gemm_f32(const float* __restrict__ A,
    const float* __restrict__ B, float* __restrict__ C, int M, int N, int K)
{
    __shared__ float As[BM][BK + 1];
    __shared__ float Bs[BK][BN + 1];
    int tid = threadIdx.y * 16 + threadIdx.x;
    int rowBase = blockIdx.y * BM;
    int colBase = blockIdx.x * BN;
    float acc[4][4] = {};
    for (int k0 = 0; k0 < K; k0 += BK) {
        for (int i = tid; i < BM * BK; i += 256) {
            int r = i >> 4, c = i & 15;
            As[r][c] = A[(size_t)(rowBase + r) * K + k0 + c];
        }
        for (int i = tid; i < BK * BN; i += 256) {
            int r = i >> 6, c = i & 63;
            Bs[r][c] = B[(size_t)(k0 + r) * N + colBase + c];
        }
        __syncthreads();
        for (int kk = 0; kk < BK; ++kk) {
            float a[4], b[4];
#pragma unroll
            for (int i = 0; i < 4; ++i) a[i] = As[threadIdx.y * 4 + i][kk];
#pragma unroll
            for (int j = 0; j < 4; ++j) b[j] = Bs[kk][threadIdx.x * 4 + j];
#pragma unroll
            for (int i = 0; i < 4; ++i)
#pragma unroll
                for (int j = 0; j < 4; ++j) acc[i][j] += a[i] * b[j];
        }
        __syncthreads();
    }
#pragma unroll
    for (int i = 0; i < 4; ++i)
#pragma unroll
        for (int j = 0; j < 4; ++j)
            C[(size_t)(rowBase + threadIdx.y * 4 + i) * N + colBase + threadIdx.x * 4 + j] = acc[i][j];
}

// ---------------- RoPE on q (columns h*128+64 .. h*128+127, in place) ----------------
__global__ __launch_bounds__(256) void rope_q_kernel(float* __restrict__ q)
{
    int idx = blockIdx.x * 256 + threadIdx.x;     // T_*H_*32 total
    int i  = idx & 31;
    int hh = (idx >> 5) & (H_ - 1);
    int t  = idx >> 9;
    int s  = t & (S_ - 1);
    float inv = __expf(-(float)i * 0.28782313662425575f);  // ln(10000)/32
    float ang = (float)s * inv;
    float c = cosf(ang), sn = sinf(ang);
    float* base = q + (size_t)t * (H_ * (DH_ + DR_)) + hh * 128 + 64;
    float t1 = base[i], t2 = base[32 + i];
    base[i]      = t1 * c - t2 * sn;
    base[32 + i] = t2 * c + t1 * sn;
}

// ---------------- RoPE on k_r (T_ x 64, in place) ----------------
__global__ __launch_bounds__(256) void rope_kr_kernel(float* __restrict__ kr)
{
    int idx = blockIdx.x * 256 + threadIdx.x;     // T_*32 total
    int i = idx & 31;
    int t = idx >> 5;
    int s = t & (S_ - 1);
    float inv = __expf(-(float)i * 0.28782313662425575f);
    float ang = (float)s * inv;
    float c = cosf(ang), sn = sinf(ang);
    float* base = kr + (size_t)t * 64;
    float t1 = base[i], t2 = base[32 + i];
    base[i]      = t1 * c - t2 * sn;
    base[32 + i] = t2 * c + t1 * sn;
}

// ---------------- attention: one block per (b,h,qpos) ----------------
__global__ __launch_bounds__(256) void attn_kernel(const float* __restrict__ q,
    const float* __restrict__ kc, const float* __restrict__ v,
    const float* __restrict__ kr, float* __restrict__ ctx)
{
    int blk = blockIdx.x;
    int qp = blk & (S_ - 1);
    int hh = (blk >> 11) & (H_ - 1);
    int b  = blk >> 15;
    int tid = threadIdx.x;
    int tq = b * S_ + qp;

    __shared__ float qv[128];
    __shared__ float sc[S_];
    __shared__ float red[256];

    if (tid < 128) qv[tid] = q[(size_t)tq * 2048 + hh * 128 + tid];
    __syncthreads();

    const float scale = 0.08838834764831845f;  // 1/sqrt(128)
    int kmax = qp;
    for (int k = tid; k <= kmax; k += 256) {
        const float* kcp = kc + (size_t)(b * S_ + k) * 1024 + hh * 64;
        const float* krp = kr + (size_t)(b * S_ + k) * 64;
        float s = 0.f;
#pragma unroll 8
        for (int d = 0; d < 64; ++d) s += qv[d] * kcp[d];
#pragma unroll 8
        for (int d = 0; d < 64; ++d) s += qv[64 + d] * krp[d];
        sc[k] = s * scale;
    }
    __syncthreads();

    float m = -1e30f;
    for (int k = tid; k <= kmax; k += 256) m = fmaxf(m, sc[k]);
    red[tid] = m; __syncthreads();
    for (int o = 128; o > 0; o >>= 1) { if (tid < o) red[tid] = fmaxf(red[tid], red[tid + o]); __syncthreads(); }
    m = red[0]; __syncthreads();

    float ssum = 0.f;
    for (int k = tid; k <= kmax; k += 256) { float e = __expf(sc[k] - m); sc[k] = e; ssum += e; }
    red[tid] = ssum; __syncthreads();
    for (int o = 128; o > 0; o >>= 1) { if (tid < o) red[tid] += red[tid + o]; __syncthreads(); }
    float inv = 1.f / red[0];

    int g = tid >> 6, d = tid & 63;
    float acc = 0.f;
    for (int k = g; k <= kmax; k += 4)
        acc += sc[k] * v[(size_t)(b * S_ + k) * 1024 + hh * 64 + d];
    __syncthreads();          // protect red reuse
    red[tid] = acc; __syncthreads();
    if (g == 0) {
        float r = (red[d] + red[64 + d] + red[128 + d] + red[192 + d]) * inv;
        ctx[(size_t)tq * 1024 + hh * 64 + d] = r;
    }
}

// ---------------- residual add: x_mid = x + attn_out ----------------
__global__ __launch_bounds__(256) void add_kernel(const float* __restrict__ x,
    const float* __restrict__ a, float* __restrict__ o, int n)
{
    int i = blockIdx.x * 256 + threadIdx.x;
    if (i < n) o[i] = x[i] + a[i];
}

// ---------------- gate + top2 ----------------
__global__ __launch_bounds__(256) void gate_kernel(const float* __restrict__ h2,
    const float* __restrict__ gw, float* __restrict__ dense_w)
{
    int t = blockIdx.x, tid = threadIdx.x;
    float part[8] = {0, 0, 0, 0, 0, 0, 0, 0};
    const float* hp = h2 + (size_t)t * D_;
    for (int d = tid; d < D_; d += 256) {
        float hd = hp[d];
#pragma unroll
        for (int e = 0; e < 8; ++e) part[e] += hd * gw[d * 8 + e];
    }
    __shared__ float red[256];
    __shared__ float logits[8];
    for (int e = 0; e < 8; ++e) {
        red[tid] = part[e]; __syncthreads();
        for (int o = 128; o > 0; o >>= 1) { if (tid < o) red[tid] += red[tid + o]; __syncthreads(); }
        if (tid == 0) logits[e] = red[0];
        __syncthreads();
    }
    if (tid == 0) {
        float mx = logits[0];
        for (int e = 1; e < 8; ++e) mx = fmaxf(mx, logits[e]);
        float p[8], s = 0.f;
        for (int e = 0; e < 8; ++e) { p[e] = __expf(logits[e] - mx); s += p[e]; }
        for (int e = 0; e < 8; ++e) p[e] /= s;
        int i0 = 0;
        for (int e = 1; e < 8; ++e) if (p[e] > p[i0]) i0 = e;
        int i1 = (i0 == 0) ? 1 : 0;
        for (int e = 0; e < 8; ++e) { if (e == i0) continue; if (p[e] > p[i1]) i1 = e; }
        float sw = p[i0] + p[i1];
        float* dw = dense_w + (size_t)t * 8;
        for (int e = 0; e < 8; ++e) dw[e] = 0.f;
        dw[i0] = p[i0] / sw;
        dw[i1] = p[i1] / sw;
    }
}

// ---------------- fused per-token expert MLPs (2 shared + top-2 routed) ----------------
__global__ __launch_bounds__(256) void moe_kernel(const float* __restrict__ h2,
    const float* __restrict__ dense_w,
    const float* __restrict__ wr_gate, const float* __restrict__ wr_up, const float* __restrict__ wr_down,
    const float* __restrict__ ws_gate, const float* __restrict__ ws_up, const float* __restrict__ ws_down,
    const float* __restrict__ x_mid, float* __restrict__ out)
{
    int t = blockIdx.x, tid = threadIdx.x;
    __shared__ float hbuf[D_];
    __shared__ float act[DHID_];
    for (int d = tid; d < D_; d += 256) hbuf[d] = h2[(size_t)t * D_ + d];
    float acc[4] = {0.f, 0.f, 0.f, 0.f};
    __syncthreads();

    for (int p = 0; p < 2 + 8; ++p) {
        const float *Wg, *Wu, *Wd;
        float wgt;
        if (p < 2) {
            size_t off = (size_t)p * D_ * DHID_;
            Wg = ws_gate + off; Wu = ws_up + off; Wd = ws_down + (size_t)p * DHID_ * D_;
            wgt = 1.f;
        } else {
            int e = p - 2;
            wgt = dense_w[(size_t)t * 8 + e];    // uniform across block
            if (wgt == 0.f) continue;
            size_t off = (size_t)e * D_ * DHID_;
            Wg = wr_gate + off; Wu = wr_up + off; Wd = wr_down + (size_t)e * DHID_ * D_;
        }
        float g0 = 0.f, u0 = 0.f, g1 = 0.f, u1 = 0.f;
        for (int d = 0; d < D_; ++d) {
            float hd = hbuf[d];
            const float* wg = Wg + (size_t)d * DHID_;
            const float* wu = Wu + (size_t)d * DHID_;
            g0 += hd * wg[tid];
            g1 += hd * wg[tid + 256];
            u0 += hd * wu[tid];
            u1 += hd * wu[tid + 256];
        }
        float s0 = g0 / (1.f + __expf(-g0));
        float s1 = g1 / (1.f + __expf(-g1));
        act[tid] = s0 * u0;
        act[tid + 256] = s1 * u1;
        __syncthreads();
#pragma unroll
        for (int i = 0; i < 4; ++i) {
            int dd = tid + 256 * i;
            float a = 0.f;
            for (int j = 0; j < DHID_; ++j) a += act[j] * Wd[(size_t)j * D_ + dd];
            acc[i] += wgt * a;
        }
        __syncthreads();
    }
#pragma unroll
    for (int i = 0; i < 4; ++i) {
        int dd = tid + 256 * i;
        out[(size_t)t * D_ + dd] = x_mid[(size_t)t * D_ + dd] + acc[i];
    }
}

extern "C" void kernel_launch(void* const* d_in, const int* in_sizes, int n_in,
                              void* d_out, int out_size, void* d_ws, size_t ws_size,
                              hipStream_t stream)
{
    const float* x       = (const float*)d_in[0];
    // d_in[1] = mask (causal tril; handled analytically)
    const float* w_q     = (const float*)d_in[2];
    const float* w_dkv   = (const float*)d_in[3];
    const float* w_uk    = (const float*)d_in[4];
    const float* w_uv    = (const float*)d_in[5];
    const float* w_kr    = (const float*)d_in[6];
    const float* w_o     = (const float*)d_in[7];
    const float* attn_nw = (const float*)d_in[8];
    const float* mlp_nw  = (const float*)d_in[9];
    const float* gate_w  = (const float*)d_in[10];
    const float* wr_gate = (const float*)d_in[11];
    const float* wr_up   = (const float*)d_in[12];
    const float* wr_down = (const float*)d_in[13];
    const float* ws_gate = (const float*)d_in[14];
    const float* ws_up   = (const float*)d_in[15];
    const float* ws_down = (const float*)d_in[16];
    float* out = (float*)d_out;

    float* ws = (float*)d_ws;
    const size_t M1 = 1024 * 1024;
    // Peak usage 22.25M floats = 89 MB.
    float* h       = ws;                         // [0, 4M)   dead after kr gemm
    float* qb      = ws + 4 * M1;                // [4M, 12M) dead after attn
    float* latent  = ws + 12 * M1;               // [12M,14M) dead after uk/uv gemms
    float* k_c     = ws + 14 * M1;               // [14M,18M) dead after attn
    float* vb      = ws + 18 * M1;               // [18M,22M) dead after attn
    float* k_r     = ws + 22 * M1;               // [22M,22.25M) dead after attn
    float* ctx     = ws;                         // reuse [0,4M)
    float* attn_o  = ws + 12 * M1;               // reuse [12M,16M)
    float* x_mid   = ws + 16 * M1;               // reuse [16M,20M)
    float* h2      = ws + 4 * M1;                // reuse [4M,8M)
    float* dense_w = ws + 8 * M1;                // reuse [8M, +32K)

    dim3 blk(16, 16);

    rmsnorm_kernel<<<T_, 256, 0, stream>>>(x, attn_nw, h);
    gemm_f32<<<dim3(2048 / BN, T_ / BM), blk, 0, stream>>>(h, w_q, qb, T_, 2048, 1024);
    gemm_f32<<<dim3(512 / BN, T_ / BM), blk, 0, stream>>>(h, w_dkv, latent, T_, 512, 1024);
    gemm_f32<<<dim3(64 / BN, T_ / BM), blk, 0, stream>>>(h, w_kr, k_r, T_, 64, 1024);
    gemm_f32<<<dim3(1024 / BN, T_ / BM), blk, 0, stream>>>(latent, w_uk, k_c, T_, 1024, 512);
    gemm_f32<<<dim3(1024 / BN, T_ / BM), blk, 0, stream>>>(latent, w_uv, vb, T_, 1024, 512);
    rope_q_kernel<<<(T_ * H_ * 32) / 256, 256, 0, stream>>>(qb);
    rope_kr_kernel<<<(T_ * 32) / 256, 256, 0, stream>>>(k_r);
    attn_kernel<<<B_ * H_ * S_, 256, 0, stream>>>(qb, k_c, vb, k_r, ctx);
    gemm_f32<<<dim3(1024 / BN, T_ / BM), blk, 0, stream>>>(ctx, w_o, attn_o, T_, 1024, 1024);
    add_kernel<<<(T_ * D_) / 256, 256, 0, stream>>>(x, attn_o, x_mid, T_ * D_);
    rmsnorm_kernel<<<T_, 256, 0, stream>>>(x_mid, mlp_nw, h2);
    gate_kernel<<<T_, 256, 0, stream>>>(h2, gate_w, dense_w);
    moe_kernel<<<T_, 256, 0, stream>>>(h2, dense_w, wr_gate, wr_up, wr_down,
                                       ws_gate, ws_up, ws_down, x_mid, out);
}

// Round 3
// 6079.440 us; speedup vs baseline: 2.6052x; 2.6052x over previous
//
#include <hip/hip_runtime.h>
#include <hip/hip_bf16.h>
#include <stdint.h>

typedef unsigned short u16;
typedef __attribute__((ext_vector_type(8))) short short8;
typedef __attribute__((ext_vector_type(4))) float f32x4;

#define B_    2
#define S_    2048
#define D_    1024
#define H_    16
#define T_    (B_*S_)

static __device__ __forceinline__ float b2f(u16 h) { return __uint_as_float(((uint32_t)h) << 16); }
static __device__ __forceinline__ u16 f2b(float f) {
    uint32_t u = __float_as_uint(f);
    u += 0x7fffu + ((u >> 16) & 1u);          // RNE
    return (u16)(u >> 16);
}
#define MFMA(a,b,c) __builtin_amdgcn_mfma_f32_16x16x32_bf16(a,b,c,0,0,0)

// ---------------- transpose + f32->bf16 convert: out[n][k] = in[k][n] ----------------
__global__ __launch_bounds__(256) void transpose_cvt(const float* __restrict__ in,
    u16* __restrict__ out, int K, int N, long inEZ, long outEZ)
{
    __shared__ float tile[32][33];
    const int e = blockIdx.z;
    const float* ip = in + (long)e * inEZ;
    u16* op = out + (long)e * outEZ;
    int n0 = blockIdx.x * 32, k0 = blockIdx.y * 32;
    int tx = threadIdx.x, ty = threadIdx.y;   // 32 x 8
#pragma unroll
    for (int i = 0; i < 4; ++i) {
        int k = k0 + ty + 8 * i, n = n0 + tx;
        tile[ty + 8 * i][tx] = (k < K && n < N) ? ip[(long)k * N + n] : 0.f;
    }
    __syncthreads();
#pragma unroll
    for (int i = 0; i < 4; ++i) {
        int n = n0 + ty + 8 * i, k = k0 + tx;
        if (n < N && k < K) op[(long)n * K + k] = f2b(tile[tx][ty + 8 * i]);
    }
}

// ---------------- MFMA GEMM: C(MxN) = A(MxK bf16) * Bt(NxK bf16)^T ----------------
// 128x128 block tile, 4 waves (2x2), 64x64 per wave, 16x16x32 MFMA.
// mode: 0 = f32 store, 1 = bf16 store, 2 = f32 accumulate (+=)
#define TS 40   // padded LDS row stride (u16): 80B, 16B-aligned, max 2-way bank aliasing
__global__ __launch_bounds__(256) void gemm_dense(const u16* __restrict__ A,
    const u16* __restrict__ Bt, void* __restrict__ Cv, int M, int N, int K, int mode)
{
    __shared__ u16 As[128 * TS];
    __shared__ u16 Bs[128 * TS];
    const int tid = threadIdx.x, lane = tid & 63, wave = tid >> 6;
    const int wm = (wave & 1) * 64, wn = (wave >> 1) * 64;
    const int quad = lane >> 4, rr = lane & 15, q8 = quad * 8;
    const long row0 = (long)blockIdx.y * 128, col0 = (long)blockIdx.x * 128;
    f32x4 acc[4][4];
#pragma unroll
    for (int i = 0; i < 4; ++i)
#pragma unroll
        for (int j = 0; j < 4; ++j)
#pragma unroll
            for (int c = 0; c < 4; ++c) acc[i][j][c] = 0.f;
    const int srow = tid >> 1, scol = (tid & 1) * 16;
    const bool aok = (row0 + srow) < M;
    const bool bok = (col0 + srow) < N;
    const u16* ag = A + (row0 + srow) * (long)K + scol;
    const u16* bg = Bt + (col0 + srow) * (long)K + scol;
    const short8 z8 = {0,0,0,0,0,0,0,0};
    for (int k0 = 0; k0 < K; k0 += 32) {
        short8 a0 = aok ? *(const short8*)(ag + k0) : z8;
        short8 a1 = aok ? *(const short8*)(ag + k0 + 8) : z8;
        short8 b0 = bok ? *(const short8*)(bg + k0) : z8;
        short8 b1 = bok ? *(const short8*)(bg + k0 + 8) : z8;
        *(short8*)(&As[srow * TS + scol])     = a0;
        *(short8*)(&As[srow * TS + scol + 8]) = a1;
        *(short8*)(&Bs[srow * TS + scol])     = b0;
        *(short8*)(&Bs[srow * TS + scol + 8]) = b1;
        __syncthreads();
        short8 af[4], bf[4];
#pragma unroll
        for (int mi = 0; mi < 4; ++mi) af[mi] = *(const short8*)(&As[(wm + mi * 16 + rr) * TS + q8]);
#pragma unroll
        for (int ni = 0; ni < 4; ++ni) bf[ni] = *(const short8*)(&Bs[(wn + ni * 16 + rr) * TS + q8]);
#pragma unroll
        for (int mi = 0; mi < 4; ++mi)
#pragma unroll
            for (int ni = 0; ni < 4; ++ni)
                acc[mi][ni] = MFMA(af[mi], bf[ni], acc[mi][ni]);
        __syncthreads();
    }
#pragma unroll
    for (int mi = 0; mi < 4; ++mi)
#pragma unroll
        for (int ni = 0; ni < 4; ++ni)
#pragma unroll
            for (int rg = 0; rg < 4; ++rg) {
                long r = row0 + wm + mi * 16 + quad * 4 + rg;
                long c = col0 + wn + ni * 16 + rr;
                if (r < M && c < N) {
                    float v = acc[mi][ni][rg];
                    if (mode == 0)      ((float*)Cv)[r * N + c] = v;
                    else if (mode == 1) ((u16*)Cv)[r * N + c] = f2b(v);
                    else                ((float*)Cv)[r * N + c] += v;
                }
            }
}

// ---------------- gathered-row GEMM for routed experts (gate/up) ----------------
__global__ __launch_bounds__(256) void gemm_gather(const u16* __restrict__ H2,
    const u16* __restrict__ BtAll, u16* __restrict__ C,
    const int* __restrict__ cnt, const int* __restrict__ off,
    const int* __restrict__ elist, int N, int K)
{
    const int e = blockIdx.z;
    const int cntE = cnt[e], offE = off[e];
    const int m0 = blockIdx.y * 128;
    if (m0 >= cntE) return;
    const u16* Bt = BtAll + (long)e * N * K;
    __shared__ u16 As[128 * TS];
    __shared__ u16 Bs[128 * TS];
    const int tid = threadIdx.x, lane = tid & 63, wave = tid >> 6;
    const int wm = (wave & 1) * 64, wn = (wave >> 1) * 64;
    const int quad = lane >> 4, rr = lane & 15, q8 = quad * 8;
    const long col0 = (long)blockIdx.x * 128;
    f32x4 acc[4][4];
#pragma unroll
    for (int i = 0; i < 4; ++i)
#pragma unroll
        for (int j = 0; j < 4; ++j)
#pragma unroll
            for (int c = 0; c < 4; ++c) acc[i][j][c] = 0.f;
    const int srow = tid >> 1, scol = (tid & 1) * 16;
    const int ar = m0 + srow;
    const int tok = (ar < cntE) ? elist[offE + ar] : -1;
    const u16* ag = H2 + (long)(tok < 0 ? 0 : tok) * K + scol;
    const bool aok = tok >= 0;
    const bool bok = (col0 + srow) < N;
    const u16* bg = Bt + (col0 + srow) * (long)K + scol;
    const short8 z8 = {0,0,0,0,0,0,0,0};
    for (int k0 = 0; k0 < K; k0 += 32) {
        short8 a0 = aok ? *(const short8*)(ag + k0) : z8;
        short8 a1 = aok ? *(const short8*)(ag + k0 + 8) : z8;
        short8 b0 = bok ? *(const short8*)(bg + k0) : z8;
        short8 b1 = bok ? *(const short8*)(bg + k0 + 8) : z8;
        *(short8*)(&As[srow * TS + scol])     = a0;
        *(short8*)(&As[srow * TS + scol + 8]) = a1;
        *(short8*)(&Bs[srow * TS + scol])     = b0;
        *(short8*)(&Bs[srow * TS + scol + 8]) = b1;
        __syncthreads();
        short8 af[4], bf[4];
#pragma unroll
        for (int mi = 0; mi < 4; ++mi) af[mi] = *(const short8*)(&As[(wm + mi * 16 + rr) * TS + q8]);
#pragma unroll
        for (int ni = 0; ni < 4; ++ni) bf[ni] = *(const short8*)(&Bs[(wn + ni * 16 + rr) * TS + q8]);
#pragma unroll
        for (int mi = 0; mi < 4; ++mi)
#pragma unroll
            for (int ni = 0; ni < 4; ++ni)
                acc[mi][ni] = MFMA(af[mi], bf[ni], acc[mi][ni]);
        __syncthreads();
    }
#pragma unroll
    for (int mi = 0; mi < 4; ++mi)
#pragma unroll
        for (int ni = 0; ni < 4; ++ni)
#pragma unroll
            for (int rg = 0; rg < 4; ++rg) {
                int ml = wm + mi * 16 + quad * 4 + rg;
                long c = col0 + wn + ni * 16 + rr;
                if (m0 + ml < cntE && c < N)
                    C[(long)(offE + m0 + ml) * N + c] = f2b(acc[mi][ni][rg]);
            }
}

// ---------------- routed down-proj GEMM with weighted scatter-add ----------------
__global__ __launch_bounds__(256) void gemm_rdown(const u16* __restrict__ Act,
    const u16* __restrict__ BtAll, float* __restrict__ acc_out,
    const int* __restrict__ cnt, const int* __restrict__ off,
    const int* __restrict__ elist, const float* __restrict__ ewgt, int N, int K)
{
    const int e = blockIdx.z;
    const int cntE = cnt[e], offE = off[e];
    const int m0 = blockIdx.y * 128;
    if (m0 >= cntE) return;
    const u16* Bt = BtAll + (long)e * N * K;
    __shared__ u16 As[128 * TS];
    __shared__ u16 Bs[128 * TS];
    const int tid = threadIdx.x, lane = tid & 63, wave = tid >> 6;
    const int wm = (wave & 1) * 64, wn = (wave >> 1) * 64;
    const int quad = lane >> 4, rr = lane & 15, q8 = quad * 8;
    const long col0 = (long)blockIdx.x * 128;
    f32x4 acc[4][4];
#pragma unroll
    for (int i = 0; i < 4; ++i)
#pragma unroll
        for (int j = 0; j < 4; ++j)
#pragma unroll
            for (int c = 0; c < 4; ++c) acc[i][j][c] = 0.f;
    const int srow = tid >> 1, scol = (tid & 1) * 16;
    int ar = offE + m0 + srow; if (ar > 8191) ar = 8191;   // clamp: garbage rows are store-guarded
    const u16* ag = Act + (long)ar * K + scol;
    const bool bok = (col0 + srow) < N;
    const u16* bg = Bt + (col0 + srow) * (long)K + scol;
    const short8 z8 = {0,0,0,0,0,0,0,0};
    for (int k0 = 0; k0 < K; k0 += 32) {
        short8 a0 = *(const short8*)(ag + k0);
        short8 a1 = *(const short8*)(ag + k0 + 8);
        short8 b0 = bok ? *(const short8*)(bg + k0) : z8;
        short8 b1 = bok ? *(const short8*)(bg + k0 + 8) : z8;
        *(short8*)(&As[srow * TS + scol])     = a0;
        *(short8*)(&As[srow * TS + scol + 8]) = a1;
        *(short8*)(&Bs[srow * TS + scol])     = b0;
        *(short8*)(&Bs[srow * TS + scol + 8]) = b1;
        __syncthreads();
        short8 af[4], bf[4];
#pragma unroll
        for (int mi = 0; mi < 4; ++mi) af[mi] = *(const short8*)(&As[(wm + mi * 16 + rr) * TS + q8]);
#pragma unroll
        for (int ni = 0; ni < 4; ++ni) bf[ni] = *(const short8*)(&Bs[(wn + ni * 16 + rr) * TS + q8]);
#pragma unroll
        for (int mi = 0; mi < 4; ++mi)
#pragma unroll
            for (int ni = 0; ni < 4; ++ni)
                acc[mi][ni] = MFMA(af[mi], bf[ni], acc[mi][ni]);
        __syncthreads();
    }
#pragma unroll
    for (int mi = 0; mi < 4; ++mi)
#pragma unroll
        for (int ni = 0; ni < 4; ++ni)
#pragma unroll
            for (int rg = 0; rg < 4; ++rg) {
                int ml = wm + mi * 16 + quad * 4 + rg;
                if (m0 + ml < cntE) {
                    int slot = offE + m0 + ml;
                    int tok = elist[slot];
                    float w = ewgt[slot];
                    long c = col0 + wn + ni * 16 + rr;
                    atomicAdd(&acc_out[(long)tok * N + c], w * acc[mi][ni][rg]);
                }
            }
}

// ---------------- rmsnorm f32 -> bf16 ----------------
__global__ __launch_bounds__(256) void rmsnorm_kernel(const float* __restrict__ x,
    const float* __restrict__ w, u16* __restrict__ out)
{
    int t = blockIdx.x, tid = threadIdx.x;
    const float* xp = x + (size_t)t * D_;
    __shared__ float red[256];
    float s = 0.f;
    for (int d = tid; d < D_; d += 256) { float v = xp[d]; s += v * v; }
    red[tid] = s; __syncthreads();
    for (int o = 128; o > 0; o >>= 1) { if (tid < o) red[tid] += red[tid + o]; __syncthreads(); }
    float inv = rsqrtf(red[0] * (1.f / D_) + 1e-6f);
    u16* op = out + (size_t)t * D_;
    for (int d = tid; d < D_; d += 256) op[d] = f2b(xp[d] * inv * w[d]);
}

// ---------------- RoPE on q (bf16, cols h*128+64..h*128+127) ----------------
__global__ __launch_bounds__(256) void rope_q_kernel(u16* __restrict__ q)
{
    int idx = blockIdx.x * 256 + threadIdx.x;     // T_*H_*32 total
    int i  = idx & 31;
    int hh = (idx >> 5) & (H_ - 1);
    int t  = idx >> 9;
    int s  = t & (S_ - 1);
    float inv = __expf(-(float)i * 0.28782313662425575f);  // ln(10000)/32
    float ang = (float)s * inv;
    float c = cosf(ang), sn = sinf(ang);
    u16* base = q + (size_t)t * 2048 + hh * 128 + 64;
    float t1 = b2f(base[i]), t2 = b2f(base[32 + i]);
    base[i]      = f2b(t1 * c - t2 * sn);
    base[32 + i] = f2b(t2 * c + t1 * sn);
}

// ---------------- RoPE on k_r (f32, T_ x 64) ----------------
__global__ __launch_bounds__(256) void rope_kr_kernel(float* __restrict__ kr)
{
    int idx = blockIdx.x * 256 + threadIdx.x;     // T_*32 total
    int i = idx & 31;
    int t = idx >> 5;
    int s = t & (S_ - 1);
    float inv = __expf(-(float)i * 0.28782313662425575f);
    float ang = (float)s * inv;
    float c = cosf(ang), sn = sinf(ang);
    float* base = kr + (size_t)t * 64;
    float t1 = base[i], t2 = base[32 + i];
    base[i]      = t1 * c - t2 * sn;
    base[32 + i] = t2 * c + t1 * sn;
}

// ---------------- attention: one block per (b,h,qpos); bf16 q/k/v, f32 kr ----------------
__global__ __launch_bounds__(256) void attn_kernel(const u16* __restrict__ q,
    const u16* __restrict__ kc, const u16* __restrict__ v,
    const float* __restrict__ kr, u16* __restrict__ ctx)
{
    int blk = blockIdx.x;
    int qp = blk & (S_ - 1);
    int hh = (blk >> 11) & (H_ - 1);
    int b  = blk >> 15;
    int tid = threadIdx.x;
    int tq = b * S_ + qp;

    __shared__ float qv[128];
    __shared__ float sc[S_];
    __shared__ float red[256];

    if (tid < 128) qv[tid] = b2f(q[(size_t)tq * 2048 + hh * 128 + tid]);
    __syncthreads();

    const float scale = 0.08838834764831845f;  // 1/sqrt(128)
    int kmax = qp;
    for (int k = tid; k <= kmax; k += 256) {
        const u16* kcp = kc + (size_t)(b * S_ + k) * 1024 + hh * 64;
        const float* krp = kr + (size_t)(b * S_ + k) * 64;
        float s = 0.f;
#pragma unroll
        for (int dq = 0; dq < 8; ++dq) {
            short8 kv8 = *(const short8*)(kcp + dq * 8);
#pragma unroll
            for (int j = 0; j < 8; ++j) s += qv[dq * 8 + j] * b2f((u16)kv8[j]);
        }
#pragma unroll
        for (int dq = 0; dq < 16; ++dq) {
            float4 kv = *(const float4*)(krp + dq * 4);
            s += qv[64 + dq * 4 + 0] * kv.x + qv[64 + dq * 4 + 1] * kv.y
               + qv[64 + dq * 4 + 2] * kv.z + qv[64 + dq * 4 + 3] * kv.w;
        }
        sc[k] = s * scale;
    }
    __syncthreads();

    float m = -1e30f;
    for (int k = tid; k <= kmax; k += 256) m = fmaxf(m, sc[k]);
    red[tid] = m; __syncthreads();
    for (int o = 128; o > 0; o >>= 1) { if (tid < o) red[tid] = fmaxf(red[tid], red[tid + o]); __syncthreads(); }
    m = red[0]; __syncthreads();

    float ssum = 0.f;
    for (int k = tid; k <= kmax; k += 256) { float e = __expf(sc[k] - m); sc[k] = e; ssum += e; }
    red[tid] = ssum; __syncthreads();
    for (int o = 128; o > 0; o >>= 1) { if (tid < o) red[tid] += red[tid + o]; __syncthreads(); }
    float inv = 1.f / red[0];

    int g = tid >> 6, d = tid & 63;
    float acc = 0.f;
    for (int k = g; k <= kmax; k += 4)
        acc += sc[k] * b2f(v[(size_t)(b * S_ + k) * 1024 + hh * 64 + d]);
    __syncthreads();
    red[tid] = acc; __syncthreads();
    if (g == 0) {
        float r = (red[d] + red[64 + d] + red[128 + d] + red[192 + d]) * inv;
        ctx[(size_t)tq * 1024 + hh * 64 + d] = f2b(r);
    }
}

// ---------------- residual add ----------------
__global__ __launch_bounds__(256) void add_kernel(const float* __restrict__ x,
    const float* __restrict__ a, float* __restrict__ o, int n)
{
    int i = blockIdx.x * 256 + threadIdx.x;
    if (i < n) o[i] = x[i] + a[i];
}

// ---------------- zero moe_acc + meta ----------------
__global__ __launch_bounds__(256) void zero_kernel(float* __restrict__ acc, int n,
    int* __restrict__ ints, int nints)
{
    int i = blockIdx.x * 256 + threadIdx.x;
    if (i < n) acc[i] = 0.f;
    if (i < nints) ints[i] = 0;
}

// ---------------- gate: f32 rmsnorm + logits + top2 + counting ----------------
__global__ __launch_bounds__(256) void gate_kernel(const float* __restrict__ xm,
    const float* __restrict__ nw, const float* __restrict__ gw,
    int* __restrict__ tok_e, float* __restrict__ tok_w, int* __restrict__ cnt)
{
    int t = blockIdx.x, tid = threadIdx.x;
    const float* xp = xm + (size_t)t * D_;
    __shared__ float red[256];
    float s = 0.f;
    for (int d = tid; d < D_; d += 256) { float v = xp[d]; s += v * v; }
    red[tid] = s; __syncthreads();
    for (int o = 128; o > 0; o >>= 1) { if (tid < o) red[tid] += red[tid + o]; __syncthreads(); }
    float inv = rsqrtf(red[0] * (1.f / D_) + 1e-6f);
    __syncthreads();
    float part[8] = {0,0,0,0,0,0,0,0};
    for (int d = tid; d < D_; d += 256) {
        float hv = xp[d] * inv * nw[d];
#pragma unroll
        for (int e = 0; e < 8; ++e) part[e] += hv * gw[d * 8 + e];
    }
    __shared__ float logits[8];
    for (int e = 0; e < 8; ++e) {
        red[tid] = part[e]; __syncthreads();
        for (int o = 128; o > 0; o >>= 1) { if (tid < o) red[tid] += red[tid + o]; __syncthreads(); }
        if (tid == 0) logits[e] = red[0];
        __syncthreads();
    }
    if (tid == 0) {
        float mx = logits[0];
        for (int e = 1; e < 8; ++e) mx = fmaxf(mx, logits[e]);
        float p[8], ps = 0.f;
        for (int e = 0; e < 8; ++e) { p[e] = __expf(logits[e] - mx); ps += p[e]; }
        for (int e = 0; e < 8; ++e) p[e] /= ps;
        int i0 = 0;
        for (int e = 1; e < 8; ++e) if (p[e] > p[i0]) i0 = e;
        int i1 = (i0 == 0) ? 1 : 0;
        for (int e = 0; e < 8; ++e) { if (e == i0) continue; if (p[e] > p[i1]) i1 = e; }
        float sw = p[i0] + p[i1];
        tok_e[2 * t] = i0;  tok_e[2 * t + 1] = i1;
        tok_w[2 * t] = p[i0] / sw;  tok_w[2 * t + 1] = p[i1] / sw;
        atomicAdd(&cnt[i0], 1);
        atomicAdd(&cnt[i1], 1);
    }
}

// ---------------- prefix: counts -> offsets + cursors ----------------
__global__ void prefix_kernel(const int* __restrict__ cnt, int* __restrict__ off,
    int* __restrict__ cursor)
{
    if (threadIdx.x == 0 && blockIdx.x == 0) {
        int s = 0;
        for (int e = 0; e < 8; ++e) { off[e] = s; cursor[e] = s; s += cnt[e]; }
    }
}

// ---------------- scatter token ids into expert segments ----------------
__global__ __launch_bounds__(256) void scatter_kernel(const int* __restrict__ tok_e,
    const float* __restrict__ tok_w, int* __restrict__ cursor,
    int* __restrict__ elist, float* __restrict__ ewgt)
{
    int t = blockIdx.x * 256 + threadIdx.x;
    if (t >= T_) return;
    for (int j = 0; j < 2; ++j) {
        int e = tok_e[2 * t + j];
        int slot = atomicAdd(&cursor[e], 1);
        elist[slot] = t;
        ewgt[slot] = tok_w[2 * t + j];
    }
}

// ---------------- silu(g)*u -> bf16 act ----------------
__global__ __launch_bounds__(256) void silu_mul(const u16* __restrict__ g,
    const u16* __restrict__ u, u16* __restrict__ act, int n)
{
    int i = blockIdx.x * 256 + threadIdx.x;
    if (i < n) {
        float gv = b2f(g[i]), uv = b2f(u[i]);
        float sv = gv / (1.f + __expf(-gv));
        act[i] = f2b(sv * uv);
    }
}

// ---------------- final: out = x_mid + moe_acc ----------------
__global__ __launch_bounds__(256) void final_kernel(const float* __restrict__ xm,
    const float* __restrict__ acc, float* __restrict__ out, int n)
{
    int i = blockIdx.x * 256 + threadIdx.x;
    if (i < n) out[i] = xm[i] + acc[i];
}

// ---------------- workspace layout (bytes); peak ~103.3 MB ----------------
#define OFF_WQ      0UL
#define OFF_WDKV    4194304UL
#define OFF_WKR     5242880UL
#define OFF_WUK     5373952UL
#define OFF_WUV     6422528UL
#define OFF_WO      7471104UL
#define OFF_WRG     9568256UL
#define OFF_WRU     17956864UL
#define OFF_WRD     26345472UL
#define OFF_WSG     34734080UL
#define OFF_WSU     36831232UL
#define OFF_WSD     38928384UL
#define OFF_XMID    41025536UL
#define OFF_SLOTA   57802752UL   // h -> ctx -> h2 (8MB)
#define OFF_SLOTB   66191360UL   // qb -> attn_o -> g (16MB slot)
#define OFF_U       74579968UL   // u (upper half of slot B)
#define OFF_SLOTC   82968576UL   // latent(4MB)+k_r(1MB) -> act(8MB)
#define OFF_KR      87162880UL
#define OFF_SLOTD   91357184UL   // k_c(8MB)+vb(8MB) -> moe_acc(16MB)
#define OFF_VB      99745792UL
#define OFF_TOKE    108134400UL
#define OFF_TOKW    108167168UL
#define OFF_ELIST   108199936UL
#define OFF_EWGT    108232704UL
#define OFF_META    108265472UL

extern "C" void kernel_launch(void* const* d_in, const int* in_sizes, int n_in,
                              void* d_out, int out_size, void* d_ws, size_t ws_size,
                              hipStream_t stream)
{
    const float* x       = (const float*)d_in[0];
    const float* w_q     = (const float*)d_in[2];
    const float* w_dkv   = (const float*)d_in[3];
    const float* w_uk    = (const float*)d_in[4];
    const float* w_uv    = (const float*)d_in[5];
    const float* w_kr    = (const float*)d_in[6];
    const float* w_o     = (const float*)d_in[7];
    const float* attn_nw = (const float*)d_in[8];
    const float* mlp_nw  = (const float*)d_in[9];
    const float* gate_w  = (const float*)d_in[10];
    const float* wr_gate = (const float*)d_in[11];
    const float* wr_up   = (const float*)d_in[12];
    const float* wr_down = (const float*)d_in[13];
    const float* ws_gate = (const float*)d_in[14];
    const float* ws_up   = (const float*)d_in[15];
    const float* ws_down = (const float*)d_in[16];
    float* out = (float*)d_out;

    char* W = (char*)d_ws;
    u16* wq_t   = (u16*)(W + OFF_WQ);
    u16* wdkv_t = (u16*)(W + OFF_WDKV);
    u16* wkr_t  = (u16*)(W + OFF_WKR);
    u16* wuk_t  = (u16*)(W + OFF_WUK);
    u16* wuv_t  = (u16*)(W + OFF_WUV);
    u16* wo_t   = (u16*)(W + OFF_WO);
    u16* wrg_t  = (u16*)(W + OFF_WRG);
    u16* wru_t  = (u16*)(W + OFF_WRU);
    u16* wrd_t  = (u16*)(W + OFF_WRD);
    u16* wsg_t  = (u16*)(W + OFF_WSG);
    u16* wsu_t  = (u16*)(W + OFF_WSU);
    u16* wsd_t  = (u16*)(W + OFF_WSD);
    float* x_mid = (float*)(W + OFF_XMID);
    u16* h      = (u16*)(W + OFF_SLOTA);
    u16* ctx    = (u16*)(W + OFF_SLOTA);
    u16* h2     = (u16*)(W + OFF_SLOTA);
    u16* qb     = (u16*)(W + OFF_SLOTB);
    float* attn_o = (float*)(W + OFF_SLOTB);
    u16* gbuf   = (u16*)(W + OFF_SLOTB);
    u16* ubuf   = (u16*)(W + OFF_U);
    u16* latent = (u16*)(W + OFF_SLOTC);
    u16* act    = (u16*)(W + OFF_SLOTC);
    float* k_r  = (float*)(W + OFF_KR);
    u16* k_c    = (u16*)(W + OFF_SLOTD);
    u16* vb     = (u16*)(W + OFF_VB);
    float* moe_acc = (float*)(W + OFF_SLOTD);
    int*   tok_e = (int*)(W + OFF_TOKE);
    float* tok_w = (float*)(W + OFF_TOKW);
    int*   elist = (int*)(W + OFF_ELIST);
    float* ewgt  = (float*)(W + OFF_EWGT);
    int*   meta  = (int*)(W + OFF_META);
    int* cnt = meta, * off = meta + 8, * cursor = meta + 16;

    dim3 tb(32, 8);
    // weight transposes (f32 KxN -> bf16 NxK)
    transpose_cvt<<<dim3(64, 32, 1), tb, 0, stream>>>(w_q,     wq_t,   1024, 2048, 0, 0);
    transpose_cvt<<<dim3(16, 32, 1), tb, 0, stream>>>(w_dkv,   wdkv_t, 1024, 512,  0, 0);
    transpose_cvt<<<dim3(2,  32, 1), tb, 0, stream>>>(w_kr,    wkr_t,  1024, 64,   0, 0);
    transpose_cvt<<<dim3(32, 16, 1), tb, 0, stream>>>(w_uk,    wuk_t,  512,  1024, 0, 0);
    transpose_cvt<<<dim3(32, 16, 1), tb, 0, stream>>>(w_uv,    wuv_t,  512,  1024, 0, 0);
    transpose_cvt<<<dim3(32, 32, 1), tb, 0, stream>>>(w_o,     wo_t,   1024, 1024, 0, 0);
    transpose_cvt<<<dim3(16, 32, 8), tb, 0, stream>>>(wr_gate, wrg_t,  1024, 512,  524288, 524288);
    transpose_cvt<<<dim3(16, 32, 8), tb, 0, stream>>>(wr_up,   wru_t,  1024, 512,  524288, 524288);
    transpose_cvt<<<dim3(32, 16, 8), tb, 0, stream>>>(wr_down, wrd_t,  512,  1024, 524288, 524288);
    transpose_cvt<<<dim3(16, 32, 2), tb, 0, stream>>>(ws_gate, wsg_t,  1024, 512,  524288, 524288);
    transpose_cvt<<<dim3(16, 32, 2), tb, 0, stream>>>(ws_up,   wsu_t,  1024, 512,  524288, 524288);
    transpose_cvt<<<dim3(32, 16, 2), tb, 0, stream>>>(ws_down, wsd_t,  512,  1024, 524288, 524288);

    // attention path
    rmsnorm_kernel<<<T_, 256, 0, stream>>>(x, attn_nw, h);
    gemm_dense<<<dim3(16, 32), 256, 0, stream>>>(h, wq_t, qb, 4096, 2048, 1024, 1);
    gemm_dense<<<dim3(4, 32), 256, 0, stream>>>(h, wdkv_t, latent, 4096, 512, 1024, 1);
    gemm_dense<<<dim3(1, 32), 256, 0, stream>>>(h, wkr_t, k_r, 4096, 64, 1024, 0);
    gemm_dense<<<dim3(8, 32), 256, 0, stream>>>(latent, wuk_t, k_c, 4096, 1024, 512, 1);
    gemm_dense<<<dim3(8, 32), 256, 0, stream>>>(latent, wuv_t, vb, 4096, 1024, 512, 1);
    rope_q_kernel<<<(T_ * H_ * 32) / 256, 256, 0, stream>>>(qb);
    rope_kr_kernel<<<(T_ * 32) / 256, 256, 0, stream>>>(k_r);
    attn_kernel<<<B_ * H_ * S_, 256, 0, stream>>>(qb, k_c, vb, k_r, ctx);
    gemm_dense<<<dim3(8, 32), 256, 0, stream>>>(ctx, wo_t, attn_o, 4096, 1024, 1024, 0);
    add_kernel<<<(T_ * D_) / 256, 256, 0, stream>>>(x, attn_o, x_mid, T_ * D_);

    // MoE path
    rmsnorm_kernel<<<T_, 256, 0, stream>>>(x_mid, mlp_nw, h2);
    zero_kernel<<<(T_ * D_) / 256, 256, 0, stream>>>(moe_acc, T_ * D_, meta, 24);
    gate_kernel<<<T_, 256, 0, stream>>>(x_mid, mlp_nw, gate_w, tok_e, tok_w, cnt);
    prefix_kernel<<<1, 64, 0, stream>>>(cnt, off, cursor);
    scatter_kernel<<<16, 256, 0, stream>>>(tok_e, tok_w, cursor, elist, ewgt);
    gemm_gather<<<dim3(4, 32, 8), 256, 0, stream>>>(h2, wrg_t, gbuf, cnt, off, elist, 512, 1024);
    gemm_gather<<<dim3(4, 32, 8), 256, 0, stream>>>(h2, wru_t, ubuf, cnt, off, elist, 512, 1024);
    silu_mul<<<(8192 * 512) / 256, 256, 0, stream>>>(gbuf, ubuf, act, 8192 * 512);
    gemm_rdown<<<dim3(8, 32, 8), 256, 0, stream>>>(act, wrd_t, moe_acc, cnt, off, elist, ewgt, 1024, 512);
    for (int e = 0; e < 2; ++e) {
        gemm_dense<<<dim3(4, 32), 256, 0, stream>>>(h2, wsg_t + (size_t)e * 524288, gbuf, 4096, 512, 1024, 1);
        gemm_dense<<<dim3(4, 32), 256, 0, stream>>>(h2, wsu_t + (size_t)e * 524288, ubuf, 4096, 512, 1024, 1);
        silu_mul<<<(4096 * 512) / 256, 256, 0, stream>>>(gbuf, ubuf, act, 4096 * 512);
        gemm_dense<<<dim3(8, 32), 256, 0, stream>>>(act, wsd_t + (size_t)e * 524288, moe_acc, 4096, 1024, 512, 2);
    }
    final_kernel<<<(T_ * D_) / 256, 256, 0, stream>>>(x_mid, moe_acc, out, T_ * D_);
}

// Round 4
// 1117.572 us; speedup vs baseline: 14.1719x; 5.4399x over previous
//
#include <hip/hip_runtime.h>
#include <hip/hip_bf16.h>
#include <stdint.h>

typedef unsigned short u16;
typedef __attribute__((ext_vector_type(8))) short short8;
typedef __attribute__((ext_vector_type(4))) float f32x4;

#define B_    2
#define S_    2048
#define D_    1024
#define H_    16
#define T_    (B_*S_)

static __device__ __forceinline__ float b2f(u16 h) { return __uint_as_float(((uint32_t)h) << 16); }
static __device__ __forceinline__ u16 f2b(float f) {
    uint32_t u = __float_as_uint(f);
    u += 0x7fffu + ((u >> 16) & 1u);          // RNE
    return (u16)(u >> 16);
}
#define MFMA(a,b,c) __builtin_amdgcn_mfma_f32_16x16x32_bf16(a,b,c,0,0,0)

// ---------------- transpose + f32->bf16 convert: out[n][k] = in[k][n] ----------------
__global__ __launch_bounds__(256) void transpose_cvt(const float* __restrict__ in,
    u16* __restrict__ out, int K, int N, long inEZ, long outEZ)
{
    __shared__ float tile[32][33];
    const int e = blockIdx.z;
    const float* ip = in + (long)e * inEZ;
    u16* op = out + (long)e * outEZ;
    int n0 = blockIdx.x * 32, k0 = blockIdx.y * 32;
    int tx = threadIdx.x, ty = threadIdx.y;   // 32 x 8
#pragma unroll
    for (int i = 0; i < 4; ++i) {
        int k = k0 + ty + 8 * i, n = n0 + tx;
        tile[ty + 8 * i][tx] = (k < K && n < N) ? ip[(long)k * N + n] : 0.f;
    }
    __syncthreads();
#pragma unroll
    for (int i = 0; i < 4; ++i) {
        int n = n0 + ty + 8 * i, k = k0 + tx;
        if (n < N && k < K) op[(long)n * K + k] = f2b(tile[tx][ty + 8 * i]);
    }
}

// ---------------- MFMA GEMM: C(MxN) = A(MxK bf16) * Bt(NxK bf16)^T ----------------
// 128x128 block tile, 4 waves (2x2), 64x64 per wave, 16x16x32 MFMA.
// mode: 0 = f32 store, 1 = bf16 store, 2 = f32 accumulate (+=)
#define TS 40   // padded LDS row stride (u16): 80B, 16B-aligned, max 2-way bank aliasing
__global__ __launch_bounds__(256) void gemm_dense(const u16* __restrict__ A,
    const u16* __restrict__ Bt, void* __restrict__ Cv, int M, int N, int K, int mode)
{
    __shared__ u16 As[128 * TS];
    __shared__ u16 Bs[128 * TS];
    const int tid = threadIdx.x, lane = tid & 63, wave = tid >> 6;
    const int wm = (wave & 1) * 64, wn = (wave >> 1) * 64;
    const int quad = lane >> 4, rr = lane & 15, q8 = quad * 8;
    const long row0 = (long)blockIdx.y * 128, col0 = (long)blockIdx.x * 128;
    f32x4 acc[4][4];
#pragma unroll
    for (int i = 0; i < 4; ++i)
#pragma unroll
        for (int j = 0; j < 4; ++j)
#pragma unroll
            for (int c = 0; c < 4; ++c) acc[i][j][c] = 0.f;
    const int srow = tid >> 1, scol = (tid & 1) * 16;
    const bool aok = (row0 + srow) < M;
    const bool bok = (col0 + srow) < N;
    const u16* ag = A + (row0 + srow) * (long)K + scol;
    const u16* bg = Bt + (col0 + srow) * (long)K + scol;
    const short8 z8 = {0,0,0,0,0,0,0,0};
    for (int k0 = 0; k0 < K; k0 += 32) {
        short8 a0 = aok ? *(const short8*)(ag + k0) : z8;
        short8 a1 = aok ? *(const short8*)(ag + k0 + 8) : z8;
        short8 b0 = bok ? *(const short8*)(bg + k0) : z8;
        short8 b1 = bok ? *(const short8*)(bg + k0 + 8) : z8;
        *(short8*)(&As[srow * TS + scol])     = a0;
        *(short8*)(&As[srow * TS + scol + 8]) = a1;
        *(short8*)(&Bs[srow * TS + scol])     = b0;
        *(short8*)(&Bs[srow * TS + scol + 8]) = b1;
        __syncthreads();
        short8 af[4], bf[4];
#pragma unroll
        for (int mi = 0; mi < 4; ++mi) af[mi] = *(const short8*)(&As[(wm + mi * 16 + rr) * TS + q8]);
#pragma unroll
        for (int ni = 0; ni < 4; ++ni) bf[ni] = *(const short8*)(&Bs[(wn + ni * 16 + rr) * TS + q8]);
#pragma unroll
        for (int mi = 0; mi < 4; ++mi)
#pragma unroll
            for (int ni = 0; ni < 4; ++ni)
                acc[mi][ni] = MFMA(af[mi], bf[ni], acc[mi][ni]);
        __syncthreads();
    }
#pragma unroll
    for (int mi = 0; mi < 4; ++mi)
#pragma unroll
        for (int ni = 0; ni < 4; ++ni)
#pragma unroll
            for (int rg = 0; rg < 4; ++rg) {
                long r = row0 + wm + mi * 16 + quad * 4 + rg;
                long c = col0 + wn + ni * 16 + rr;
                if (r < M && c < N) {
                    float v = acc[mi][ni][rg];
                    if (mode == 0)      ((float*)Cv)[r * N + c] = v;
                    else if (mode == 1) ((u16*)Cv)[r * N + c] = f2b(v);
                    else                ((float*)Cv)[r * N + c] += v;
                }
            }
}

// ---------------- gathered-row GEMM for routed experts (gate/up) ----------------
__global__ __launch_bounds__(256) void gemm_gather(const u16* __restrict__ H2,
    const u16* __restrict__ BtAll, u16* __restrict__ C,
    const int* __restrict__ cnt, const int* __restrict__ off,
    const int* __restrict__ elist, int N, int K)
{
    const int e = blockIdx.z;
    const int cntE = cnt[e], offE = off[e];
    const int m0 = blockIdx.y * 128;
    if (m0 >= cntE) return;
    const u16* Bt = BtAll + (long)e * N * K;
    __shared__ u16 As[128 * TS];
    __shared__ u16 Bs[128 * TS];
    const int tid = threadIdx.x, lane = tid & 63, wave = tid >> 6;
    const int wm = (wave & 1) * 64, wn = (wave >> 1) * 64;
    const int quad = lane >> 4, rr = lane & 15, q8 = quad * 8;
    const long col0 = (long)blockIdx.x * 128;
    f32x4 acc[4][4];
#pragma unroll
    for (int i = 0; i < 4; ++i)
#pragma unroll
        for (int j = 0; j < 4; ++j)
#pragma unroll
            for (int c = 0; c < 4; ++c) acc[i][j][c] = 0.f;
    const int srow = tid >> 1, scol = (tid & 1) * 16;
    const int ar = m0 + srow;
    const int tok = (ar < cntE) ? elist[offE + ar] : -1;
    const u16* ag = H2 + (long)(tok < 0 ? 0 : tok) * K + scol;
    const bool aok = tok >= 0;
    const bool bok = (col0 + srow) < N;
    const u16* bg = Bt + (col0 + srow) * (long)K + scol;
    const short8 z8 = {0,0,0,0,0,0,0,0};
    for (int k0 = 0; k0 < K; k0 += 32) {
        short8 a0 = aok ? *(const short8*)(ag + k0) : z8;
        short8 a1 = aok ? *(const short8*)(ag + k0 + 8) : z8;
        short8 b0 = bok ? *(const short8*)(bg + k0) : z8;
        short8 b1 = bok ? *(const short8*)(bg + k0 + 8) : z8;
        *(short8*)(&As[srow * TS + scol])     = a0;
        *(short8*)(&As[srow * TS + scol + 8]) = a1;
        *(short8*)(&Bs[srow * TS + scol])     = b0;
        *(short8*)(&Bs[srow * TS + scol + 8]) = b1;
        __syncthreads();
        short8 af[4], bf[4];
#pragma unroll
        for (int mi = 0; mi < 4; ++mi) af[mi] = *(const short8*)(&As[(wm + mi * 16 + rr) * TS + q8]);
#pragma unroll
        for (int ni = 0; ni < 4; ++ni) bf[ni] = *(const short8*)(&Bs[(wn + ni * 16 + rr) * TS + q8]);
#pragma unroll
        for (int mi = 0; mi < 4; ++mi)
#pragma unroll
            for (int ni = 0; ni < 4; ++ni)
                acc[mi][ni] = MFMA(af[mi], bf[ni], acc[mi][ni]);
        __syncthreads();
    }
#pragma unroll
    for (int mi = 0; mi < 4; ++mi)
#pragma unroll
        for (int ni = 0; ni < 4; ++ni)
#pragma unroll
            for (int rg = 0; rg < 4; ++rg) {
                int ml = wm + mi * 16 + quad * 4 + rg;
                long c = col0 + wn + ni * 16 + rr;
                if (m0 + ml < cntE && c < N)
                    C[(long)(offE + m0 + ml) * N + c] = f2b(acc[mi][ni][rg]);
            }
}

// ---------------- routed down-proj GEMM with weighted scatter-add ----------------
__global__ __launch_bounds__(256) void gemm_rdown(const u16* __restrict__ Act,
    const u16* __restrict__ BtAll, float* __restrict__ acc_out,
    const int* __restrict__ cnt, const int* __restrict__ off,
    const int* __restrict__ elist, const float* __restrict__ ewgt, int N, int K)
{
    const int e = blockIdx.z;
    const int cntE = cnt[e], offE = off[e];
    const int m0 = blockIdx.y * 128;
    if (m0 >= cntE) return;
    const u16* Bt = BtAll + (long)e * N * K;
    __shared__ u16 As[128 * TS];
    __shared__ u16 Bs[128 * TS];
    const int tid = threadIdx.x, lane = tid & 63, wave = tid >> 6;
    const int wm = (wave & 1) * 64, wn = (wave >> 1) * 64;
    const int quad = lane >> 4, rr = lane & 15, q8 = quad * 8;
    const long col0 = (long)blockIdx.x * 128;
    f32x4 acc[4][4];
#pragma unroll
    for (int i = 0; i < 4; ++i)
#pragma unroll
        for (int j = 0; j < 4; ++j)
#pragma unroll
            for (int c = 0; c < 4; ++c) acc[i][j][c] = 0.f;
    const int srow = tid >> 1, scol = (tid & 1) * 16;
    int ar = offE + m0 + srow; if (ar > 8191) ar = 8191;   // clamp: garbage rows are store-guarded
    const u16* ag = Act + (long)ar * K + scol;
    const bool bok = (col0 + srow) < N;
    const u16* bg = Bt + (col0 + srow) * (long)K + scol;
    const short8 z8 = {0,0,0,0,0,0,0,0};
    for (int k0 = 0; k0 < K; k0 += 32) {
        short8 a0 = *(const short8*)(ag + k0);
        short8 a1 = *(const short8*)(ag + k0 + 8);
        short8 b0 = bok ? *(const short8*)(bg + k0) : z8;
        short8 b1 = bok ? *(const short8*)(bg + k0 + 8) : z8;
        *(short8*)(&As[srow * TS + scol])     = a0;
        *(short8*)(&As[srow * TS + scol + 8]) = a1;
        *(short8*)(&Bs[srow * TS + scol])     = b0;
        *(short8*)(&Bs[srow * TS + scol + 8]) = b1;
        __syncthreads();
        short8 af[4], bf[4];
#pragma unroll
        for (int mi = 0; mi < 4; ++mi) af[mi] = *(const short8*)(&As[(wm + mi * 16 + rr) * TS + q8]);
#pragma unroll
        for (int ni = 0; ni < 4; ++ni) bf[ni] = *(const short8*)(&Bs[(wn + ni * 16 + rr) * TS + q8]);
#pragma unroll
        for (int mi = 0; mi < 4; ++mi)
#pragma unroll
            for (int ni = 0; ni < 4; ++ni)
                acc[mi][ni] = MFMA(af[mi], bf[ni], acc[mi][ni]);
        __syncthreads();
    }
#pragma unroll
    for (int mi = 0; mi < 4; ++mi)
#pragma unroll
        for (int ni = 0; ni < 4; ++ni)
#pragma unroll
            for (int rg = 0; rg < 4; ++rg) {
                int ml = wm + mi * 16 + quad * 4 + rg;
                if (m0 + ml < cntE) {
                    int slot = offE + m0 + ml;
                    int tok = elist[slot];
                    float w = ewgt[slot];
                    long c = col0 + wn + ni * 16 + rr;
                    atomicAdd(&acc_out[(long)tok * N + c], w * acc[mi][ni][rg]);
                }
            }
}

// ---------------- rmsnorm f32 -> bf16 ----------------
__global__ __launch_bounds__(256) void rmsnorm_kernel(const float* __restrict__ x,
    const float* __restrict__ w, u16* __restrict__ out)
{
    int t = blockIdx.x, tid = threadIdx.x;
    const float* xp = x + (size_t)t * D_;
    __shared__ float red[256];
    float s = 0.f;
    for (int d = tid; d < D_; d += 256) { float v = xp[d]; s += v * v; }
    red[tid] = s; __syncthreads();
    for (int o = 128; o > 0; o >>= 1) { if (tid < o) red[tid] += red[tid + o]; __syncthreads(); }
    float inv = rsqrtf(red[0] * (1.f / D_) + 1e-6f);
    u16* op = out + (size_t)t * D_;
    for (int d = tid; d < D_; d += 256) op[d] = f2b(xp[d] * inv * w[d]);
}

// ---------------- RoPE on q (bf16, cols h*128+64..h*128+127) ----------------
__global__ __launch_bounds__(256) void rope_q_kernel(u16* __restrict__ q)
{
    int idx = blockIdx.x * 256 + threadIdx.x;     // T_*H_*32 total
    int i  = idx & 31;
    int hh = (idx >> 5) & (H_ - 1);
    int t  = idx >> 9;
    int s  = t & (S_ - 1);
    float inv = __expf(-(float)i * 0.28782313662425575f);  // ln(10000)/32
    float ang = (float)s * inv;
    float c = cosf(ang), sn = sinf(ang);
    u16* base = q + (size_t)t * 2048 + hh * 128 + 64;
    float t1 = b2f(base[i]), t2 = b2f(base[32 + i]);
    base[i]      = f2b(t1 * c - t2 * sn);
    base[32 + i] = f2b(t2 * c + t1 * sn);
}

// ---------------- RoPE on k_r (bf16, T_ x 64, in place) ----------------
__global__ __launch_bounds__(256) void rope_kr_kernel(u16* __restrict__ kr)
{
    int idx = blockIdx.x * 256 + threadIdx.x;     // T_*32 total
    int i = idx & 31;
    int t = idx >> 5;
    int s = t & (S_ - 1);
    float inv = __expf(-(float)i * 0.28782313662425575f);
    float ang = (float)s * inv;
    float c = cosf(ang), sn = sinf(ang);
    u16* base = kr + (size_t)t * 64;
    float t1 = b2f(base[i]), t2 = b2f(base[32 + i]);
    base[i]      = f2b(t1 * c - t2 * sn);
    base[32 + i] = f2b(t2 * c + t1 * sn);
}

// ---------------- flash attention (MFMA): BQ=64 x BK=64, d=128, dv=64 ----------------
// One block (4 waves) per (b,h,q-tile); wave owns 16 Q-rows (full rows).
// P relayout C->A via per-wave LDS band (m120-verified pattern).
#define QS 136   // Qs/Ks row stride (128+8)
#define PS 72    // Ps/Vs row stride (64+8)
__global__ __launch_bounds__(256) void attn_flash(const u16* __restrict__ q,
    const u16* __restrict__ kc, const u16* __restrict__ v,
    const u16* __restrict__ kr, u16* __restrict__ ctx)
{
    const int qt = 31 - (blockIdx.x & 31);        // heaviest tiles first
    const int bh = blockIdx.x >> 5;
    const int b = bh >> 4, h = bh & 15;
    const int q0 = qt * 64;
    const int tid = threadIdx.x, lane = tid & 63, wave = tid >> 6;
    const int quad = lane >> 4, rr = lane & 15, q8 = quad * 8;
    const int wrow0 = wave * 16;

    __shared__ u16 Qs[64 * QS];   // [qrow][d0..127]
    __shared__ u16 Ks[64 * QS];   // [key][d0..127]
    __shared__ u16 Vs[64 * PS];   // [vdim][key]  (transposed)
    __shared__ u16 Ps[64 * PS];   // [qrow][key]

    const long tbase = (long)b * S_ + q0;
    // stage Q tile: 64 rows x 128 cols (cols h*128..h*128+127 of qb)
#pragma unroll
    for (int i = 0; i < 4; ++i) {
        int c = tid + i * 256;                    // 1024 chunks of 8
        int row = c >> 4, cc = (c & 15) * 8;
        *(short8*)&Qs[row * QS + cc] = *(const short8*)&q[(tbase + row) * 2048 + h * 128 + cc];
    }

    f32x4 accO[4];
    float m_i[4], l_i[4];
#pragma unroll
    for (int ni = 0; ni < 4; ++ni)
#pragma unroll
        for (int rg = 0; rg < 4; ++rg) accO[ni][rg] = 0.f;
#pragma unroll
    for (int rg = 0; rg < 4; ++rg) { m_i[rg] = -3e38f; l_i[rg] = 0.f; }

    const float sc = 0.08838834764831845f * 1.4426950408889634f;  // (1/sqrt(128))*log2(e)

    for (int kt = 0; kt <= qt; ++kt) {
        const int k0 = kt * 64;
        const long kb = (long)b * S_ + k0;
        // stage K tile: cols 0..63 from k_c[h], 64..127 from k_r
#pragma unroll
        for (int i = 0; i < 2; ++i) {
            int c = tid + i * 256;                // 512 chunks
            int row = c >> 3, cc = (c & 7) * 8;
            *(short8*)&Ks[row * QS + cc] = *(const short8*)&kc[(kb + row) * 1024 + h * 64 + cc];
        }
#pragma unroll
        for (int i = 0; i < 2; ++i) {
            int c = tid + i * 256;
            int row = c >> 3, cc = (c & 7) * 8;
            *(short8*)&Ks[row * QS + 64 + cc] = *(const short8*)&kr[(kb + row) * 64 + cc];
        }
        // stage V transposed: Vs[vdim][key]; consecutive lanes -> consecutive keys
#pragma unroll
        for (int i = 0; i < 2; ++i) {
            int c = tid + i * 256;
            int row = c & 63, cc8 = (c >> 6) * 8;  // row=key, cc8=vdim0
            short8 vv = *(const short8*)&v[(kb + row) * 1024 + h * 64 + cc8];
#pragma unroll
            for (int j = 0; j < 8; ++j) Vs[(cc8 + j) * PS + row] = (u16)vv[j];
        }
        __syncthreads();

        // S = Q·K^T for this wave's 16 rows x 64 keys
        f32x4 accS[4];
#pragma unroll
        for (int ni = 0; ni < 4; ++ni)
#pragma unroll
            for (int rg = 0; rg < 4; ++rg) accS[ni][rg] = 0.f;
#pragma unroll
        for (int d0 = 0; d0 < 128; d0 += 32) {
            short8 af = *(const short8*)&Qs[(wrow0 + rr) * QS + d0 + q8];
            short8 bf[4];
#pragma unroll
            for (int ni = 0; ni < 4; ++ni) bf[ni] = *(const short8*)&Ks[(ni * 16 + rr) * QS + d0 + q8];
#pragma unroll
            for (int ni = 0; ni < 4; ++ni) accS[ni] = MFMA(af, bf[ni], accS[ni]);
        }
        // scale (+ causal mask on diagonal tile)
        const bool diag = (kt == qt);
#pragma unroll
        for (int ni = 0; ni < 4; ++ni)
#pragma unroll
            for (int rg = 0; rg < 4; ++rg) {
                float w = accS[ni][rg] * sc;
                if (diag) {
                    int rl = wrow0 + quad * 4 + rg;
                    int cl = ni * 16 + rr;
                    if (cl > rl) w = -1e30f;
                }
                accS[ni][rg] = w;
            }
        // row max (across ni, then across the 16 lanes of the quad group)
        float alpha[4];
#pragma unroll
        for (int rg = 0; rg < 4; ++rg) {
            float mx = fmaxf(fmaxf(accS[0][rg], accS[1][rg]), fmaxf(accS[2][rg], accS[3][rg]));
#pragma unroll
            for (int d = 1; d < 16; d <<= 1) mx = fmaxf(mx, __shfl_xor(mx, d));
            float mnew = fmaxf(m_i[rg], mx);
            alpha[rg] = exp2f(m_i[rg] - mnew);
            m_i[rg] = mnew;
        }
        // exp, partial row-sum, write P band (wave-private rows)
        float prow[4] = {0.f, 0.f, 0.f, 0.f};
#pragma unroll
        for (int ni = 0; ni < 4; ++ni)
#pragma unroll
            for (int rg = 0; rg < 4; ++rg) {
                float p = exp2f(accS[ni][rg] - m_i[rg]);
                prow[rg] += p;
                Ps[(wrow0 + quad * 4 + rg) * PS + ni * 16 + rr] = f2b(p);
            }
#pragma unroll
        for (int rg = 0; rg < 4; ++rg) {
#pragma unroll
            for (int d = 1; d < 16; d <<= 1) prow[rg] += __shfl_xor(prow[rg], d);
            l_i[rg] = l_i[rg] * alpha[rg] + prow[rg];
        }
        // rescale O
#pragma unroll
        for (int ni = 0; ni < 4; ++ni)
#pragma unroll
            for (int rg = 0; rg < 4; ++rg) accO[ni][rg] *= alpha[rg];
        // O += P·V  (P rows wave-private; compiler inserts lgkm waits for LDS RAW)
#pragma unroll
        for (int d0 = 0; d0 < 64; d0 += 32) {
            short8 af = *(const short8*)&Ps[(wrow0 + rr) * PS + d0 + q8];
            short8 bf[4];
#pragma unroll
            for (int ni = 0; ni < 4; ++ni) bf[ni] = *(const short8*)&Vs[(ni * 16 + rr) * PS + d0 + q8];
#pragma unroll
            for (int ni = 0; ni < 4; ++ni) accO[ni] = MFMA(af, bf[ni], accO[ni]);
        }
        __syncthreads();
    }
    // epilogue: ctx[t][h*64+vd] = O/l
#pragma unroll
    for (int ni = 0; ni < 4; ++ni)
#pragma unroll
        for (int rg = 0; rg < 4; ++rg) {
            long t = tbase + wrow0 + quad * 4 + rg;
            ctx[t * 1024 + h * 64 + ni * 16 + rr] = f2b(accO[ni][rg] / l_i[rg]);
        }
}

// ---------------- residual add ----------------
__global__ __launch_bounds__(256) void add_kernel(const float* __restrict__ x,
    const float* __restrict__ a, float* __restrict__ o, int n)
{
    int i = blockIdx.x * 256 + threadIdx.x;
    if (i < n) o[i] = x[i] + a[i];
}

// ---------------- zero moe_acc + meta ----------------
__global__ __launch_bounds__(256) void zero_kernel(float* __restrict__ acc, int n,
    int* __restrict__ ints, int nints)
{
    int i = blockIdx.x * 256 + threadIdx.x;
    if (i < n) acc[i] = 0.f;
    if (i < nints) ints[i] = 0;
}

// ---------------- gate: f32 rmsnorm + logits + top2 + counting ----------------
__global__ __launch_bounds__(256) void gate_kernel(const float* __restrict__ xm,
    const float* __restrict__ nw, const float* __restrict__ gw,
    int* __restrict__ tok_e, float* __restrict__ tok_w, int* __restrict__ cnt)
{
    int t = blockIdx.x, tid = threadIdx.x;
    const float* xp = xm + (size_t)t * D_;
    __shared__ float red[256];
    float s = 0.f;
    for (int d = tid; d < D_; d += 256) { float v = xp[d]; s += v * v; }
    red[tid] = s; __syncthreads();
    for (int o = 128; o > 0; o >>= 1) { if (tid < o) red[tid] += red[tid + o]; __syncthreads(); }
    float inv = rsqrtf(red[0] * (1.f / D_) + 1e-6f);
    __syncthreads();
    float part[8] = {0,0,0,0,0,0,0,0};
    for (int d = tid; d < D_; d += 256) {
        float hv = xp[d] * inv * nw[d];
#pragma unroll
        for (int e = 0; e < 8; ++e) part[e] += hv * gw[d * 8 + e];
    }
    __shared__ float logits[8];
    for (int e = 0; e < 8; ++e) {
        red[tid] = part[e]; __syncthreads();
        for (int o = 128; o > 0; o >>= 1) { if (tid < o) red[tid] += red[tid + o]; __syncthreads(); }
        if (tid == 0) logits[e] = red[0];
        __syncthreads();
    }
    if (tid == 0) {
        float mx = logits[0];
        for (int e = 1; e < 8; ++e) mx = fmaxf(mx, logits[e]);
        float p[8], ps = 0.f;
        for (int e = 0; e < 8; ++e) { p[e] = __expf(logits[e] - mx); ps += p[e]; }
        for (int e = 0; e < 8; ++e) p[e] /= ps;
        int i0 = 0;
        for (int e = 1; e < 8; ++e) if (p[e] > p[i0]) i0 = e;
        int i1 = (i0 == 0) ? 1 : 0;
        for (int e = 0; e < 8; ++e) { if (e == i0) continue; if (p[e] > p[i1]) i1 = e; }
        float sw = p[i0] + p[i1];
        tok_e[2 * t] = i0;  tok_e[2 * t + 1] = i1;
        tok_w[2 * t] = p[i0] / sw;  tok_w[2 * t + 1] = p[i1] / sw;
        atomicAdd(&cnt[i0], 1);
        atomicAdd(&cnt[i1], 1);
    }
}

// ---------------- prefix: counts -> offsets + cursors ----------------
__global__ void prefix_kernel(const int* __restrict__ cnt, int* __restrict__ off,
    int* __restrict__ cursor)
{
    if (threadIdx.x == 0 && blockIdx.x == 0) {
        int s = 0;
        for (int e = 0; e < 8; ++e) { off[e] = s; cursor[e] = s; s += cnt[e]; }
    }
}

// ---------------- scatter token ids into expert segments ----------------
__global__ __launch_bounds__(256) void scatter_kernel(const int* __restrict__ tok_e,
    const float* __restrict__ tok_w, int* __restrict__ cursor,
    int* __restrict__ elist, float* __restrict__ ewgt)
{
    int t = blockIdx.x * 256 + threadIdx.x;
    if (t >= T_) return;
    for (int j = 0; j < 2; ++j) {
        int e = tok_e[2 * t + j];
        int slot = atomicAdd(&cursor[e], 1);
        elist[slot] = t;
        ewgt[slot] = tok_w[2 * t + j];
    }
}

// ---------------- silu(g)*u -> bf16 act ----------------
__global__ __launch_bounds__(256) void silu_mul(const u16* __restrict__ g,
    const u16* __restrict__ u, u16* __restrict__ act, int n)
{
    int i = blockIdx.x * 256 + threadIdx.x;
    if (i < n) {
        float gv = b2f(g[i]), uv = b2f(u[i]);
        float sv = gv / (1.f + __expf(-gv));
        act[i] = f2b(sv * uv);
    }
}

// ---------------- final: out = x_mid + moe_acc ----------------
__global__ __launch_bounds__(256) void final_kernel(const float* __restrict__ xm,
    const float* __restrict__ acc, float* __restrict__ out, int n)
{
    int i = blockIdx.x * 256 + threadIdx.x;
    if (i < n) out[i] = xm[i] + acc[i];
}

// ---------------- workspace layout (bytes); peak ~103.3 MB ----------------
#define OFF_WQ      0UL
#define OFF_WDKV    4194304UL
#define OFF_WKR     5242880UL
#define OFF_WUK     5373952UL
#define OFF_WUV     6422528UL
#define OFF_WO      7471104UL
#define OFF_WRG     9568256UL
#define OFF_WRU     17956864UL
#define OFF_WRD     26345472UL
#define OFF_WSG     34734080UL
#define OFF_WSU     36831232UL
#define OFF_WSD     38928384UL
#define OFF_XMID    41025536UL
#define OFF_SLOTA   57802752UL   // h -> ctx -> h2 (8MB)
#define OFF_SLOTB   66191360UL   // qb -> attn_o -> g (16MB slot)
#define OFF_U       74579968UL   // u (upper half of slot B)
#define OFF_SLOTC   82968576UL   // latent(4MB) -> act(8MB)
#define OFF_KR      87162880UL   // k_r bf16 (512KB used of 4MB gap)
#define OFF_SLOTD   91357184UL   // k_c(8MB)+vb(8MB) -> moe_acc(16MB)
#define OFF_VB      99745792UL
#define OFF_TOKE    108134400UL
#define OFF_TOKW    108167168UL
#define OFF_ELIST   108199936UL
#define OFF_EWGT    108232704UL
#define OFF_META    108265472UL

extern "C" void kernel_launch(void* const* d_in, const int* in_sizes, int n_in,
                              void* d_out, int out_size, void* d_ws, size_t ws_size,
                              hipStream_t stream)
{
    const float* x       = (const float*)d_in[0];
    const float* w_q     = (const float*)d_in[2];
    const float* w_dkv   = (const float*)d_in[3];
    const float* w_uk    = (const float*)d_in[4];
    const float* w_uv    = (const float*)d_in[5];
    const float* w_kr    = (const float*)d_in[6];
    const float* w_o     = (const float*)d_in[7];
    const float* attn_nw = (const float*)d_in[8];
    const float* mlp_nw  = (const float*)d_in[9];
    const float* gate_w  = (const float*)d_in[10];
    const float* wr_gate = (const float*)d_in[11];
    const float* wr_up   = (const float*)d_in[12];
    const float* wr_down = (const float*)d_in[13];
    const float* ws_gate = (const float*)d_in[14];
    const float* ws_up   = (const float*)d_in[15];
    const float* ws_down = (const float*)d_in[16];
    float* out = (float*)d_out;

    char* W = (char*)d_ws;
    u16* wq_t   = (u16*)(W + OFF_WQ);
    u16* wdkv_t = (u16*)(W + OFF_WDKV);
    u16* wkr_t  = (u16*)(W + OFF_WKR);
    u16* wuk_t  = (u16*)(W + OFF_WUK);
    u16* wuv_t  = (u16*)(W + OFF_WUV);
    u16* wo_t   = (u16*)(W + OFF_WO);
    u16* wrg_t  = (u16*)(W + OFF_WRG);
    u16* wru_t  = (u16*)(W + OFF_WRU);
    u16* wrd_t  = (u16*)(W + OFF_WRD);
    u16* wsg_t  = (u16*)(W + OFF_WSG);
    u16* wsu_t  = (u16*)(W + OFF_WSU);
    u16* wsd_t  = (u16*)(W + OFF_WSD);
    float* x_mid = (float*)(W + OFF_XMID);
    u16* h      = (u16*)(W + OFF_SLOTA);
    u16* ctx    = (u16*)(W + OFF_SLOTA);
    u16* h2     = (u16*)(W + OFF_SLOTA);
    u16* qb     = (u16*)(W + OFF_SLOTB);
    float* attn_o = (float*)(W + OFF_SLOTB);
    u16* gbuf   = (u16*)(W + OFF_SLOTB);
    u16* ubuf   = (u16*)(W + OFF_U);
    u16* latent = (u16*)(W + OFF_SLOTC);
    u16* act    = (u16*)(W + OFF_SLOTC);
    u16* krb    = (u16*)(W + OFF_KR);
    u16* k_c    = (u16*)(W + OFF_SLOTD);
    u16* vb     = (u16*)(W + OFF_VB);
    float* moe_acc = (float*)(W + OFF_SLOTD);
    int*   tok_e = (int*)(W + OFF_TOKE);
    float* tok_w = (float*)(W + OFF_TOKW);
    int*   elist = (int*)(W + OFF_ELIST);
    float* ewgt  = (float*)(W + OFF_EWGT);
    int*   meta  = (int*)(W + OFF_META);
    int* cnt = meta, * off = meta + 8, * cursor = meta + 16;

    dim3 tb(32, 8);
    // weight transposes (f32 KxN -> bf16 NxK)
    transpose_cvt<<<dim3(64, 32, 1), tb, 0, stream>>>(w_q,     wq_t,   1024, 2048, 0, 0);
    transpose_cvt<<<dim3(16, 32, 1), tb, 0, stream>>>(w_dkv,   wdkv_t, 1024, 512,  0, 0);
    transpose_cvt<<<dim3(2,  32, 1), tb, 0, stream>>>(w_kr,    wkr_t,  1024, 64,   0, 0);
    transpose_cvt<<<dim3(32, 16, 1), tb, 0, stream>>>(w_uk,    wuk_t,  512,  1024, 0, 0);
    transpose_cvt<<<dim3(32, 16, 1), tb, 0, stream>>>(w_uv,    wuv_t,  512,  1024, 0, 0);
    transpose_cvt<<<dim3(32, 32, 1), tb, 0, stream>>>(w_o,     wo_t,   1024, 1024, 0, 0);
    transpose_cvt<<<dim3(16, 32, 8), tb, 0, stream>>>(wr_gate, wrg_t,  1024, 512,  524288, 524288);
    transpose_cvt<<<dim3(16, 32, 8), tb, 0, stream>>>(wr_up,   wru_t,  1024, 512,  524288, 524288);
    transpose_cvt<<<dim3(32, 16, 8), tb, 0, stream>>>(wr_down, wrd_t,  512,  1024, 524288, 524288);
    transpose_cvt<<<dim3(16, 32, 2), tb, 0, stream>>>(ws_gate, wsg_t,  1024, 512,  524288, 524288);
    transpose_cvt<<<dim3(16, 32, 2), tb, 0, stream>>>(ws_up,   wsu_t,  1024, 512,  524288, 524288);
    transpose_cvt<<<dim3(32, 16, 2), tb, 0, stream>>>(ws_down, wsd_t,  512,  1024, 524288, 524288);

    // attention path
    rmsnorm_kernel<<<T_, 256, 0, stream>>>(x, attn_nw, h);
    gemm_dense<<<dim3(16, 32), 256, 0, stream>>>(h, wq_t, qb, 4096, 2048, 1024, 1);
    gemm_dense<<<dim3(4, 32), 256, 0, stream>>>(h, wdkv_t, latent, 4096, 512, 1024, 1);
    gemm_dense<<<dim3(1, 32), 256, 0, stream>>>(h, wkr_t, krb, 4096, 64, 1024, 1);
    gemm_dense<<<dim3(8, 32), 256, 0, stream>>>(latent, wuk_t, k_c, 4096, 1024, 512, 1);
    gemm_dense<<<dim3(8, 32), 256, 0, stream>>>(latent, wuv_t, vb, 4096, 1024, 512, 1);
    rope_q_kernel<<<(T_ * H_ * 32) / 256, 256, 0, stream>>>(qb);
    rope_kr_kernel<<<(T_ * 32) / 256, 256, 0, stream>>>(krb);
    attn_flash<<<32 * 32, 256, 0, stream>>>(qb, k_c, vb, krb, ctx);
    gemm_dense<<<dim3(8, 32), 256, 0, stream>>>(ctx, wo_t, attn_o, 4096, 1024, 1024, 0);
    add_kernel<<<(T_ * D_) / 256, 256, 0, stream>>>(x, attn_o, x_mid, T_ * D_);

    // MoE path
    rmsnorm_kernel<<<T_, 256, 0, stream>>>(x_mid, mlp_nw, h2);
    zero_kernel<<<(T_ * D_) / 256, 256, 0, stream>>>(moe_acc, T_ * D_, meta, 24);
    gate_kernel<<<T_, 256, 0, stream>>>(x_mid, mlp_nw, gate_w, tok_e, tok_w, cnt);
    prefix_kernel<<<1, 64, 0, stream>>>(cnt, off, cursor);
    scatter_kernel<<<16, 256, 0, stream>>>(tok_e, tok_w, cursor, elist, ewgt);
    gemm_gather<<<dim3(4, 32, 8), 256, 0, stream>>>(h2, wrg_t, gbuf, cnt, off, elist, 512, 1024);
    gemm_gather<<<dim3(4, 32, 8), 256, 0, stream>>>(h2, wru_t, ubuf, cnt, off, elist, 512, 1024);
    silu_mul<<<(8192 * 512) / 256, 256, 0, stream>>>(gbuf, ubuf, act, 8192 * 512);
    gemm_rdown<<<dim3(8, 32, 8), 256, 0, stream>>>(act, wrd_t, moe_acc, cnt, off, elist, ewgt, 1024, 512);
    for (int e = 0; e < 2; ++e) {
        gemm_dense<<<dim3(4, 32), 256, 0, stream>>>(h2, wsg_t + (size_t)e * 524288, gbuf, 4096, 512, 1024, 1);
        gemm_dense<<<dim3(4, 32), 256, 0, stream>>>(h2, wsu_t + (size_t)e * 524288, ubuf, 4096, 512, 1024, 1);
        silu_mul<<<(4096 * 512) / 256, 256, 0, stream>>>(gbuf, ubuf, act, 4096 * 512);
        gemm_dense<<<dim3(8, 32), 256, 0, stream>>>(act, wsd_t + (size_t)e * 524288, moe_acc, 4096, 1024, 512, 2);
    }
    final_kernel<<<(T_ * D_) / 256, 256, 0, stream>>>(x_mid, moe_acc, out, T_ * D_);
}

// Round 5
// 829.700 us; speedup vs baseline: 19.0890x; 1.3470x over previous
//
#include <hip/hip_runtime.h>
#include <hip/hip_bf16.h>
#include <stdint.h>

typedef unsigned short u16;
typedef __attribute__((ext_vector_type(8))) short short8;
typedef __attribute__((ext_vector_type(4))) float f32x4;

#define B_    2
#define S_    2048
#define D_    1024
#define H_    16
#define T_    (B_*S_)

static __device__ __forceinline__ float b2f(u16 h) { return __uint_as_float(((uint32_t)h) << 16); }
static __device__ __forceinline__ u16 f2b(float f) {
    uint32_t u = __float_as_uint(f);
    u += 0x7fffu + ((u >> 16) & 1u);          // RNE
    return (u16)(u >> 16);
}
#define MFMA(a,b,c) __builtin_amdgcn_mfma_f32_16x16x32_bf16(a,b,c,0,0,0)

// async global->LDS, 16B per lane; lds base must be wave-uniform (lane scatter = lane*16B)
static __device__ __forceinline__ void gl2lds16(const void* g, void* l) {
    __builtin_amdgcn_global_load_lds((const __attribute__((address_space(1))) void*)g,
                                     (__attribute__((address_space(3))) void*)l, 16, 0, 0);
}

// ---------------- transpose + f32->bf16 convert: out[n][k] = in[k][n] ----------------
__global__ __launch_bounds__(256) void transpose_cvt(const float* __restrict__ in,
    u16* __restrict__ out, int K, int N, long inEZ, long outEZ)
{
    __shared__ float tile[32][33];
    const int e = blockIdx.z;
    const float* ip = in + (long)e * inEZ;
    u16* op = out + (long)e * outEZ;
    int n0 = blockIdx.x * 32, k0 = blockIdx.y * 32;
    int tx = threadIdx.x, ty = threadIdx.y;   // 32 x 8
#pragma unroll
    for (int i = 0; i < 4; ++i) {
        int k = k0 + ty + 8 * i, n = n0 + tx;
        tile[ty + 8 * i][tx] = (k < K && n < N) ? ip[(long)k * N + n] : 0.f;
    }
    __syncthreads();
#pragma unroll
    for (int i = 0; i < 4; ++i) {
        int n = n0 + ty + 8 * i, k = k0 + tx;
        if (n < N && k < K) op[(long)n * K + k] = f2b(tile[tx][ty + 8 * i]);
    }
}

// ---------------- MFMA GEMM (m97-style): C(4096xN) = A * Bt^T ----------------
// 128x128 tile, 4 waves, unpadded LDS 128x32, global_load_lds width-16 staging.
// mode: 1 = bf16 store, 2 = f32 +=, 4 = f32 dual store (resid add -> Cv and xmid)
__global__ __launch_bounds__(256) void gemm_k(const u16* __restrict__ A, long lda,
    const u16* __restrict__ Bt, void* __restrict__ Cv, long ldc, int K, int mode,
    const float* __restrict__ resid, float* __restrict__ xmid)
{
    __shared__ u16 As[128 * 32];
    __shared__ u16 Bs[128 * 32];
    const int tid = threadIdx.x, lane = tid & 63, wave = tid >> 6;
    const int wm = (wave & 1) * 64, wn = (wave >> 1) * 64;
    const int quad = lane >> 4, rr = lane & 15, q8 = quad * 8;
    const long row0 = (long)blockIdx.y * 128, col0 = (long)blockIdx.x * 128;
    f32x4 acc[4][4];
#pragma unroll
    for (int i = 0; i < 4; ++i)
#pragma unroll
        for (int j = 0; j < 4; ++j)
#pragma unroll
            for (int c = 0; c < 4; ++c) acc[i][j][c] = 0.f;
    const int band = wave * 32;
    const u16* ga = A + (row0 + band + (lane >> 2)) * lda + (lane & 3) * 8;
    const u16* gb = Bt + (col0 + band + (lane >> 2)) * (long)K + (lane & 3) * 8;
    u16* la = &As[band * 32];
    u16* lb = &Bs[band * 32];
    for (int k0 = 0; k0 < K; k0 += 32) {
        gl2lds16(ga + k0, la);
        gl2lds16(ga + k0 + 16 * lda, la + 16 * 32);
        gl2lds16(gb + k0, lb);
        gl2lds16(gb + k0 + 16 * (long)K, lb + 16 * 32);
        __syncthreads();
        short8 af[4], bf[4];
#pragma unroll
        for (int mi = 0; mi < 4; ++mi) af[mi] = *(const short8*)&As[(wm + mi * 16 + rr) * 32 + q8];
#pragma unroll
        for (int ni = 0; ni < 4; ++ni) bf[ni] = *(const short8*)&Bs[(wn + ni * 16 + rr) * 32 + q8];
#pragma unroll
        for (int mi = 0; mi < 4; ++mi)
#pragma unroll
            for (int ni = 0; ni < 4; ++ni)
                acc[mi][ni] = MFMA(af[mi], bf[ni], acc[mi][ni]);
        __syncthreads();
    }
#pragma unroll
    for (int mi = 0; mi < 4; ++mi)
#pragma unroll
        for (int ni = 0; ni < 4; ++ni)
#pragma unroll
            for (int rg = 0; rg < 4; ++rg) {
                long r = row0 + wm + mi * 16 + quad * 4 + rg;
                long c = col0 + wn + ni * 16 + rr;
                float v = acc[mi][ni][rg];
                if (mode == 1)      ((u16*)Cv)[r * ldc + c] = f2b(v);
                else if (mode == 2) ((float*)Cv)[r * ldc + c] += v;
                else {
                    float o = v + resid[r * 1024 + c];
                    ((float*)Cv)[r * ldc + c] = o;
                    xmid[r * 1024 + c] = o;
                }
            }
}

// ---------------- gathered-row GEMM for routed experts (gate|up packed, N=1024) ----------------
__global__ __launch_bounds__(256) void gemm_gather(const u16* __restrict__ H2,
    const u16* __restrict__ BtAll, u16* __restrict__ C,
    const int* __restrict__ cnt, const int* __restrict__ off,
    const int* __restrict__ elist)
{
    const int e = blockIdx.z;
    const int cntE = cnt[e], offE = off[e];
    const int m0 = blockIdx.y * 128;
    if (m0 >= cntE) return;
    const u16* Bt = BtAll + (long)e * 1024 * 1024;
    __shared__ u16 As[128 * 32];
    __shared__ u16 Bs[128 * 32];
    const int tid = threadIdx.x, lane = tid & 63, wave = tid >> 6;
    const int wm = (wave & 1) * 64, wn = (wave >> 1) * 64;
    const int quad = lane >> 4, rr = lane & 15, q8 = quad * 8;
    const long col0 = (long)blockIdx.x * 128;
    f32x4 acc[4][4];
#pragma unroll
    for (int i = 0; i < 4; ++i)
#pragma unroll
        for (int j = 0; j < 4; ++j)
#pragma unroll
            for (int c = 0; c < 4; ++c) acc[i][j][c] = 0.f;
    const int band = wave * 32;
    int r0 = m0 + band + (lane >> 2);
    int r1 = r0 + 16;
    int tok0 = elist[offE + (r0 < cntE ? r0 : cntE - 1)];
    int tok1 = elist[offE + (r1 < cntE ? r1 : cntE - 1)];
    const u16* ga0 = H2 + (long)tok0 * 1024 + (lane & 3) * 8;
    const u16* ga1 = H2 + (long)tok1 * 1024 + (lane & 3) * 8;
    const u16* gb = Bt + (col0 + band + (lane >> 2)) * 1024L + (lane & 3) * 8;
    u16* la = &As[band * 32];
    u16* lb = &Bs[band * 32];
    for (int k0 = 0; k0 < 1024; k0 += 32) {
        gl2lds16(ga0 + k0, la);
        gl2lds16(ga1 + k0, la + 16 * 32);
        gl2lds16(gb + k0, lb);
        gl2lds16(gb + k0 + 16 * 1024, lb + 16 * 32);
        __syncthreads();
        short8 af[4], bf[4];
#pragma unroll
        for (int mi = 0; mi < 4; ++mi) af[mi] = *(const short8*)&As[(wm + mi * 16 + rr) * 32 + q8];
#pragma unroll
        for (int ni = 0; ni < 4; ++ni) bf[ni] = *(const short8*)&Bs[(wn + ni * 16 + rr) * 32 + q8];
#pragma unroll
        for (int mi = 0; mi < 4; ++mi)
#pragma unroll
            for (int ni = 0; ni < 4; ++ni)
                acc[mi][ni] = MFMA(af[mi], bf[ni], acc[mi][ni]);
        __syncthreads();
    }
#pragma unroll
    for (int mi = 0; mi < 4; ++mi)
#pragma unroll
        for (int ni = 0; ni < 4; ++ni)
#pragma unroll
            for (int rg = 0; rg < 4; ++rg) {
                int ml = wm + mi * 16 + quad * 4 + rg;
                long c = col0 + wn + ni * 16 + rr;
                if (m0 + ml < cntE)
                    C[(long)(offE + m0 + ml) * 1024 + c] = f2b(acc[mi][ni][rg]);
            }
}

// ---------------- routed down GEMM (K=512, N=1024) with weighted atomic scatter ----------------
__global__ __launch_bounds__(256) void gemm_rdown(const u16* __restrict__ Act,
    const u16* __restrict__ BtAll, float* __restrict__ acc_out,
    const int* __restrict__ cnt, const int* __restrict__ off,
    const int* __restrict__ elist, const float* __restrict__ ewgt)
{
    const int e = blockIdx.z;
    const int cntE = cnt[e], offE = off[e];
    const int m0 = blockIdx.y * 128;
    if (m0 >= cntE) return;
    const u16* Bt = BtAll + (long)e * 1024 * 512;
    __shared__ u16 As[128 * 32];
    __shared__ u16 Bs[128 * 32];
    const int tid = threadIdx.x, lane = tid & 63, wave = tid >> 6;
    const int wm = (wave & 1) * 64, wn = (wave >> 1) * 64;
    const int quad = lane >> 4, rr = lane & 15, q8 = quad * 8;
    const long col0 = (long)blockIdx.x * 128;
    f32x4 acc[4][4];
#pragma unroll
    for (int i = 0; i < 4; ++i)
#pragma unroll
        for (int j = 0; j < 4; ++j)
#pragma unroll
            for (int c = 0; c < 4; ++c) acc[i][j][c] = 0.f;
    const int band = wave * 32;
    int r0 = offE + m0 + band + (lane >> 2); if (r0 > 8191) r0 = 8191;
    int r1 = r0 + 16; if (r1 > 8191) r1 = 8191;
    const u16* ga0 = Act + (long)r0 * 512 + (lane & 3) * 8;
    const u16* ga1 = Act + (long)r1 * 512 + (lane & 3) * 8;
    const u16* gb = Bt + (col0 + band + (lane >> 2)) * 512L + (lane & 3) * 8;
    u16* la = &As[band * 32];
    u16* lb = &Bs[band * 32];
    for (int k0 = 0; k0 < 512; k0 += 32) {
        gl2lds16(ga0 + k0, la);
        gl2lds16(ga1 + k0, la + 16 * 32);
        gl2lds16(gb + k0, lb);
        gl2lds16(gb + k0 + 16 * 512, lb + 16 * 32);
        __syncthreads();
        short8 af[4], bf[4];
#pragma unroll
        for (int mi = 0; mi < 4; ++mi) af[mi] = *(const short8*)&As[(wm + mi * 16 + rr) * 32 + q8];
#pragma unroll
        for (int ni = 0; ni < 4; ++ni) bf[ni] = *(const short8*)&Bs[(wn + ni * 16 + rr) * 32 + q8];
#pragma unroll
        for (int mi = 0; mi < 4; ++mi)
#pragma unroll
            for (int ni = 0; ni < 4; ++ni)
                acc[mi][ni] = MFMA(af[mi], bf[ni], acc[mi][ni]);
        __syncthreads();
    }
#pragma unroll
    for (int mi = 0; mi < 4; ++mi)
#pragma unroll
        for (int ni = 0; ni < 4; ++ni)
#pragma unroll
            for (int rg = 0; rg < 4; ++rg) {
                int ml = wm + mi * 16 + quad * 4 + rg;
                if (m0 + ml < cntE) {
                    int slot = offE + m0 + ml;
                    long c = col0 + wn + ni * 16 + rr;
                    atomicAdd(&acc_out[(long)elist[slot] * 1024 + c], ewgt[slot] * acc[mi][ni][rg]);
                }
            }
}

// ---------------- rmsnorm f32 -> bf16 ----------------
__global__ __launch_bounds__(256) void rmsnorm_kernel(const float* __restrict__ x,
    const float* __restrict__ w, u16* __restrict__ out)
{
    int t = blockIdx.x, tid = threadIdx.x;
    const float* xp = x + (size_t)t * D_;
    __shared__ float red[256];
    float s = 0.f;
    for (int d = tid; d < D_; d += 256) { float v = xp[d]; s += v * v; }
    red[tid] = s; __syncthreads();
    for (int o = 128; o > 0; o >>= 1) { if (tid < o) red[tid] += red[tid + o]; __syncthreads(); }
    float inv = rsqrtf(red[0] * (1.f / D_) + 1e-6f);
    u16* op = out + (size_t)t * D_;
    for (int d = tid; d < D_; d += 256) op[d] = f2b(xp[d] * inv * w[d]);
}

// ---------------- RoPE on q (proj cols h*128+64..h*128+127, stride 2688) ----------------
__global__ __launch_bounds__(256) void rope_q_kernel(u16* __restrict__ proj)
{
    int idx = blockIdx.x * 256 + threadIdx.x;     // T_*H_*32 total
    int i  = idx & 31;
    int hh = (idx >> 5) & (H_ - 1);
    int t  = idx >> 9;
    int s  = t & (S_ - 1);
    float inv = __expf(-(float)i * 0.28782313662425575f);  // ln(10000)/32
    float ang = (float)s * inv;
    float c = cosf(ang), sn = sinf(ang);
    u16* base = proj + (size_t)t * 2688 + hh * 128 + 64;
    float t1 = b2f(base[i]), t2 = b2f(base[32 + i]);
    base[i]      = f2b(t1 * c - t2 * sn);
    base[32 + i] = f2b(t2 * c + t1 * sn);
}

// ---------------- RoPE on k_r (proj cols 2560..2623) ----------------
__global__ __launch_bounds__(256) void rope_kr_kernel(u16* __restrict__ proj)
{
    int idx = blockIdx.x * 256 + threadIdx.x;     // T_*32 total
    int i = idx & 31;
    int t = idx >> 5;
    int s = t & (S_ - 1);
    float inv = __expf(-(float)i * 0.28782313662425575f);
    float ang = (float)s * inv;
    float c = cosf(ang), sn = sinf(ang);
    u16* base = proj + (size_t)t * 2688 + 2560;
    float t1 = b2f(base[i]), t2 = b2f(base[32 + i]);
    base[i]      = f2b(t1 * c - t2 * sn);
    base[32 + i] = f2b(t2 * c + t1 * sn);
}

// ---------------- flash attention: BQ=128 x BK=64, Q in registers ----------------
#define KS  136  // Ks row stride u16 (128+8)
#define PS2 72   // Ps/Vs row stride u16 (64+8)
__global__ __launch_bounds__(256) void attn_flash(const u16* __restrict__ proj,
    const u16* __restrict__ kv, u16* __restrict__ ctx)
{
    const int qidx = blockIdx.x >> 5;             // 0..15, pair heavy+light across CUs
    const int qt = (qidx < 8) ? (15 - qidx) : (qidx - 8);
    const int bh = blockIdx.x & 31;
    const int b = bh >> 4, h = bh & 15;
    const int q0 = qt * 128;
    const int tid = threadIdx.x, lane = tid & 63, wave = tid >> 6;
    const int quad = lane >> 4, rr = lane & 15, q8 = quad * 8;
    const int wm2 = wave * 32;

    __shared__ u16 Ks[64 * KS];    // [key][d 0..127]
    __shared__ u16 Vs[64 * PS2];   // [vdim][key] transposed
    __shared__ u16 Ps[128 * PS2];  // [qrow][key]

    const long tbase = (long)b * S_ + q0;
    // Q fragments in registers (rows wm2+mi*16+rr, 4 chunks of 8)
    short8 qf[2][4];
#pragma unroll
    for (int mi = 0; mi < 2; ++mi)
#pragma unroll
        for (int d0 = 0; d0 < 4; ++d0)
            qf[mi][d0] = *(const short8*)&proj[(tbase + wm2 + mi * 16 + rr) * 2688 + h * 128 + d0 * 32 + q8];

    f32x4 accO[2][4];
    float m_i[2][4], l_i[2][4];
#pragma unroll
    for (int mi = 0; mi < 2; ++mi) {
#pragma unroll
        for (int ni = 0; ni < 4; ++ni)
#pragma unroll
            for (int rg = 0; rg < 4; ++rg) accO[mi][ni][rg] = 0.f;
#pragma unroll
        for (int rg = 0; rg < 4; ++rg) { m_i[mi][rg] = -3e38f; l_i[mi][rg] = 0.f; }
    }
    const float sc = 0.08838834764831845f * 1.4426950408889634f;  // 1/sqrt(128)*log2e

    const int nkt = 2 * qt + 2;
    for (int kt = 0; kt < nkt; ++kt) {
        const int k0 = kt * 64;
        const long kb = (long)b * S_ + k0;
        // stage K (cols 0..63 = k_c, 64..127 = k_r) and V^T
#pragma unroll
        for (int i = 0; i < 2; ++i) {
            int c = tid + i * 256, row = c >> 3, cc = (c & 7) * 8;
            *(short8*)&Ks[row * KS + cc] = *(const short8*)&kv[(kb + row) * 2048 + h * 64 + cc];
        }
#pragma unroll
        for (int i = 0; i < 2; ++i) {
            int c = tid + i * 256, row = c >> 3, cc = (c & 7) * 8;
            *(short8*)&Ks[row * KS + 64 + cc] = *(const short8*)&proj[(kb + row) * 2688 + 2560 + cc];
        }
#pragma unroll
        for (int i = 0; i < 2; ++i) {
            int c = tid + i * 256, row = c & 63, cc8 = (c >> 6) * 8;
            short8 vv = *(const short8*)&kv[(kb + row) * 2048 + 1024 + h * 64 + cc8];
#pragma unroll
            for (int j = 0; j < 8; ++j) Vs[(cc8 + j) * PS2 + row] = (u16)vv[j];
        }
        __syncthreads();

        bool act0 = (k0 <= q0 + wm2 + 15);
        bool act1 = (k0 <= q0 + wm2 + 31);
        f32x4 accS[2][4];
#pragma unroll
        for (int mi = 0; mi < 2; ++mi)
#pragma unroll
            for (int ni = 0; ni < 4; ++ni)
#pragma unroll
                for (int rg = 0; rg < 4; ++rg) accS[mi][ni][rg] = 0.f;
#pragma unroll
        for (int d0 = 0; d0 < 4; ++d0) {
            short8 bfk[4];
#pragma unroll
            for (int ni = 0; ni < 4; ++ni) bfk[ni] = *(const short8*)&Ks[(ni * 16 + rr) * KS + d0 * 32 + q8];
            if (act0) {
#pragma unroll
                for (int ni = 0; ni < 4; ++ni) accS[0][ni] = MFMA(qf[0][d0], bfk[ni], accS[0][ni]);
            }
            if (act1) {
#pragma unroll
                for (int ni = 0; ni < 4; ++ni) accS[1][ni] = MFMA(qf[1][d0], bfk[ni], accS[1][ni]);
            }
        }
#pragma unroll
        for (int mi = 0; mi < 2; ++mi) {
            bool act = mi ? act1 : act0;
            if (!act) continue;
            const int rbase = wm2 + mi * 16;
            bool maybe_mask = (k0 + 63 > q0 + rbase);
#pragma unroll
            for (int ni = 0; ni < 4; ++ni)
#pragma unroll
                for (int rg = 0; rg < 4; ++rg) {
                    float w = accS[mi][ni][rg] * sc;
                    if (maybe_mask) {
                        int rl = rbase + quad * 4 + rg, cl = ni * 16 + rr;
                        if (k0 + cl > q0 + rl) w = -1e30f;
                    }
                    accS[mi][ni][rg] = w;
                }
            float alpha[4];
#pragma unroll
            for (int rg = 0; rg < 4; ++rg) {
                float mx = fmaxf(fmaxf(accS[mi][0][rg], accS[mi][1][rg]),
                                 fmaxf(accS[mi][2][rg], accS[mi][3][rg]));
#pragma unroll
                for (int d = 1; d < 16; d <<= 1) mx = fmaxf(mx, __shfl_xor(mx, d));
                float mnew = fmaxf(m_i[mi][rg], mx);
                alpha[rg] = exp2f(m_i[mi][rg] - mnew);
                m_i[mi][rg] = mnew;
            }
            float prow[4] = {0.f, 0.f, 0.f, 0.f};
#pragma unroll
            for (int ni = 0; ni < 4; ++ni)
#pragma unroll
                for (int rg = 0; rg < 4; ++rg) {
                    float p = exp2f(accS[mi][ni][rg] - m_i[mi][rg]);
                    prow[rg] += p;
                    Ps[(rbase + quad * 4 + rg) * PS2 + ni * 16 + rr] = f2b(p);
                }
#pragma unroll
            for (int rg = 0; rg < 4; ++rg) {
#pragma unroll
                for (int d = 1; d < 16; d <<= 1) prow[rg] += __shfl_xor(prow[rg], d);
                l_i[mi][rg] = l_i[mi][rg] * alpha[rg] + prow[rg];
#pragma unroll
                for (int ni = 0; ni < 4; ++ni) accO[mi][ni][rg] *= alpha[rg];
            }
        }
        // O += P·V (wave-private P band; compiler inserts lgkm waits)
#pragma unroll
        for (int d0 = 0; d0 < 2; ++d0) {
            short8 bfv[4];
#pragma unroll
            for (int ni = 0; ni < 4; ++ni) bfv[ni] = *(const short8*)&Vs[(ni * 16 + rr) * PS2 + d0 * 32 + q8];
            if (act0) {
                short8 pf = *(const short8*)&Ps[(wm2 + rr) * PS2 + d0 * 32 + q8];
#pragma unroll
                for (int ni = 0; ni < 4; ++ni) accO[0][ni] = MFMA(pf, bfv[ni], accO[0][ni]);
            }
            if (act1) {
                short8 pf = *(const short8*)&Ps[(wm2 + 16 + rr) * PS2 + d0 * 32 + q8];
#pragma unroll
                for (int ni = 0; ni < 4; ++ni) accO[1][ni] = MFMA(pf, bfv[ni], accO[1][ni]);
            }
        }
        __syncthreads();
    }
#pragma unroll
    for (int mi = 0; mi < 2; ++mi)
#pragma unroll
        for (int ni = 0; ni < 4; ++ni)
#pragma unroll
            for (int rg = 0; rg < 4; ++rg) {
                long t = tbase + wm2 + mi * 16 + quad * 4 + rg;
                ctx[t * 1024 + h * 64 + ni * 16 + rr] = f2b(accO[mi][ni][rg] / l_i[mi][rg]);
            }
}

// ---------------- zero meta ----------------
__global__ void zero_meta(int* __restrict__ m) { if (threadIdx.x < 24) m[threadIdx.x] = 0; }

// ---------------- gate: f32 rmsnorm + logits + top2 + counting ----------------
__global__ __launch_bounds__(256) void gate_kernel(const float* __restrict__ xm,
    const float* __restrict__ nw, const float* __restrict__ gw,
    int* __restrict__ tok_e, float* __restrict__ tok_w, int* __restrict__ cnt)
{
    int t = blockIdx.x, tid = threadIdx.x;
    const float* xp = xm + (size_t)t * D_;
    __shared__ float red[256];
    float s = 0.f;
    for (int d = tid; d < D_; d += 256) { float v = xp[d]; s += v * v; }
    red[tid] = s; __syncthreads();
    for (int o = 128; o > 0; o >>= 1) { if (tid < o) red[tid] += red[tid + o]; __syncthreads(); }
    float inv = rsqrtf(red[0] * (1.f / D_) + 1e-6f);
    __syncthreads();
    float part[8] = {0,0,0,0,0,0,0,0};
    for (int d = tid; d < D_; d += 256) {
        float hv = xp[d] * inv * nw[d];
#pragma unroll
        for (int e = 0; e < 8; ++e) part[e] += hv * gw[d * 8 + e];
    }
    __shared__ float logits[8];
    for (int e = 0; e < 8; ++e) {
        red[tid] = part[e]; __syncthreads();
        for (int o = 128; o > 0; o >>= 1) { if (tid < o) red[tid] += red[tid + o]; __syncthreads(); }
        if (tid == 0) logits[e] = red[0];
        __syncthreads();
    }
    if (tid == 0) {
        float mx = logits[0];
        for (int e = 1; e < 8; ++e) mx = fmaxf(mx, logits[e]);
        float p[8], ps = 0.f;
        for (int e = 0; e < 8; ++e) { p[e] = __expf(logits[e] - mx); ps += p[e]; }
        for (int e = 0; e < 8; ++e) p[e] /= ps;
        int i0 = 0;
        for (int e = 1; e < 8; ++e) if (p[e] > p[i0]) i0 = e;
        int i1 = (i0 == 0) ? 1 : 0;
        for (int e = 0; e < 8; ++e) { if (e == i0) continue; if (p[e] > p[i1]) i1 = e; }
        float sw = p[i0] + p[i1];
        tok_e[2 * t] = i0;  tok_e[2 * t + 1] = i1;
        tok_w[2 * t] = p[i0] / sw;  tok_w[2 * t + 1] = p[i1] / sw;
        atomicAdd(&cnt[i0], 1);
        atomicAdd(&cnt[i1], 1);
    }
}

__global__ void prefix_kernel(const int* __restrict__ cnt, int* __restrict__ off,
    int* __restrict__ cursor)
{
    if (threadIdx.x == 0 && blockIdx.x == 0) {
        int s = 0;
        for (int e = 0; e < 8; ++e) { off[e] = s; cursor[e] = s; s += cnt[e]; }
    }
}

__global__ __launch_bounds__(256) void scatter_kernel(const int* __restrict__ tok_e,
    const float* __restrict__ tok_w, int* __restrict__ cursor,
    int* __restrict__ elist, float* __restrict__ ewgt)
{
    int t = blockIdx.x * 256 + threadIdx.x;
    if (t >= T_) return;
    for (int j = 0; j < 2; ++j) {
        int e = tok_e[2 * t + j];
        int slot = atomicAdd(&cursor[e], 1);
        elist[slot] = t;
        ewgt[slot] = tok_w[2 * t + j];
    }
}

// ---------------- silu(g)*u from packed g|u rows ----------------
__global__ __launch_bounds__(256) void silu_mul(const u16* __restrict__ gu,
    u16* __restrict__ act, int nslots)
{
    int i = blockIdx.x * 256 + threadIdx.x;
    if (i >= nslots * 512) return;
    int slot = i >> 9, j = i & 511;
    float g = b2f(gu[(long)slot * 1024 + j]);
    float u = b2f(gu[(long)slot * 1024 + 512 + j]);
    act[i] = f2b(g / (1.f + __expf(-g)) * u);
}

// ---------------- workspace layout (bytes); total ~101.1 MB ----------------
#define OFF_R0      0UL           // proj 4096x2688 bf16 (22.02M) -> wrgu 8x1024x1024 bf16
#define OFF_R1      22020096UL    // kv 4096x2048 bf16 -> gu_r 8192x1024 bf16
#define OFF_R2      38797312UL    // ctx 4096x1024 bf16 -> act_r 8192x512 bf16
#define OFF_R3      47185920UL    // h -> h2 (4096x1024 bf16)
#define OFF_WQKV    55574528UL    // 2688x1024 bf16 (5.5M)   } attn weights, later wrd
#define OFF_WUKV    61079552UL    // 2048x512 bf16 (2.1M)
#define OFF_WO      63176704UL    // 1024x1024 bf16 (2.1M)
#define OFF_WRD     55574528UL    // 8x1024x512 bf16 (8.39M) overlays attn weights (post-wo)
#define OFF_XMID    65273856UL    // 4096x1024 f32 (16.78M)
#define OFF_WSGU    82051072UL    // 2x1024x1024 bf16 (4.19M)
#define OFF_WSD     86245376UL    // 2x1024x512 bf16 (2.1M)
#define OFF_GUS     88342528UL    // 4096x1024 bf16 (8.39M)
#define OFF_ACTS    96731136UL    // 4096x512 bf16 (4.19M)
#define OFF_TOKE    100925440UL
#define OFF_TOKW    100958208UL
#define OFF_ELIST   100990976UL
#define OFF_EWGT    101023744UL
#define OFF_META    101056512UL

extern "C" void kernel_launch(void* const* d_in, const int* in_sizes, int n_in,
                              void* d_out, int out_size, void* d_ws, size_t ws_size,
                              hipStream_t stream)
{
    const float* x       = (const float*)d_in[0];
    const float* w_q     = (const float*)d_in[2];
    const float* w_dkv   = (const float*)d_in[3];
    const float* w_uk    = (const float*)d_in[4];
    const float* w_uv    = (const float*)d_in[5];
    const float* w_kr    = (const float*)d_in[6];
    const float* w_o     = (const float*)d_in[7];
    const float* attn_nw = (const float*)d_in[8];
    const float* mlp_nw  = (const float*)d_in[9];
    const float* gate_w  = (const float*)d_in[10];
    const float* wr_gate = (const float*)d_in[11];
    const float* wr_up   = (const float*)d_in[12];
    const float* wr_down = (const float*)d_in[13];
    const float* ws_gate = (const float*)d_in[14];
    const float* ws_up   = (const float*)d_in[15];
    const float* ws_down = (const float*)d_in[16];
    float* out = (float*)d_out;

    char* W = (char*)d_ws;
    u16* proj   = (u16*)(W + OFF_R0);
    u16* wrgu_t = (u16*)(W + OFF_R0);
    u16* kv     = (u16*)(W + OFF_R1);
    u16* gu_r   = (u16*)(W + OFF_R1);
    u16* ctx    = (u16*)(W + OFF_R2);
    u16* act_r  = (u16*)(W + OFF_R2);
    u16* h      = (u16*)(W + OFF_R3);
    u16* h2     = (u16*)(W + OFF_R3);
    u16* wqkv_t = (u16*)(W + OFF_WQKV);
    u16* wukv_t = (u16*)(W + OFF_WUKV);
    u16* wo_t   = (u16*)(W + OFF_WO);
    u16* wrd_t  = (u16*)(W + OFF_WRD);
    float* x_mid = (float*)(W + OFF_XMID);
    u16* wsgu_t = (u16*)(W + OFF_WSGU);
    u16* wsd_t  = (u16*)(W + OFF_WSD);
    u16* gu_s   = (u16*)(W + OFF_GUS);
    u16* act_s  = (u16*)(W + OFF_ACTS);
    int*   tok_e = (int*)(W + OFF_TOKE);
    float* tok_w = (float*)(W + OFF_TOKW);
    int*   elist = (int*)(W + OFF_ELIST);
    float* ewgt  = (float*)(W + OFF_EWGT);
    int*   meta  = (int*)(W + OFF_META);
    int* cnt = meta, * off = meta + 8, * cursor = meta + 16;

    dim3 tb(32, 8);
    // attention weights (packed qkv: rows 0..2047 q | 2048..2559 dkv | 2560..2623 kr | 2624..2687 junk)
    transpose_cvt<<<dim3(64, 32, 1), tb, 0, stream>>>(w_q,   wqkv_t,                1024, 2048, 0, 0);
    transpose_cvt<<<dim3(16, 32, 1), tb, 0, stream>>>(w_dkv, wqkv_t + 2048 * 1024,  1024, 512,  0, 0);
    transpose_cvt<<<dim3(2,  32, 1), tb, 0, stream>>>(w_kr,  wqkv_t + 2560 * 1024,  1024, 64,   0, 0);
    transpose_cvt<<<dim3(32, 16, 1), tb, 0, stream>>>(w_uk,  wukv_t,                512,  1024, 0, 0);
    transpose_cvt<<<dim3(32, 16, 1), tb, 0, stream>>>(w_uv,  wukv_t + 1024 * 512,   512,  1024, 0, 0);
    transpose_cvt<<<dim3(32, 32, 1), tb, 0, stream>>>(w_o,   wo_t,                  1024, 1024, 0, 0);

    // attention path
    rmsnorm_kernel<<<T_, 256, 0, stream>>>(x, attn_nw, h);
    gemm_k<<<dim3(21, 32), 256, 0, stream>>>(h, 1024, wqkv_t, proj, 2688, 1024, 1, nullptr, nullptr);
    rope_q_kernel<<<(T_ * H_ * 32) / 256, 256, 0, stream>>>(proj);
    rope_kr_kernel<<<(T_ * 32) / 256, 256, 0, stream>>>(proj);
    gemm_k<<<dim3(16, 32), 256, 0, stream>>>(proj + 2048, 2688, wukv_t, kv, 2048, 512, 1, nullptr, nullptr);
    attn_flash<<<512, 256, 0, stream>>>(proj, kv, ctx);
    gemm_k<<<dim3(8, 32), 256, 0, stream>>>(ctx, 1024, wo_t, out, 1024, 1024, 4, x, x_mid);

    // MoE weights (transposed after attn so they overlay dead attn buffers)
    transpose_cvt<<<dim3(16, 32, 8), tb, 0, stream>>>(wr_gate, wrgu_t,              1024, 512, 524288, 1048576);
    transpose_cvt<<<dim3(16, 32, 8), tb, 0, stream>>>(wr_up,   wrgu_t + 512 * 1024, 1024, 512, 524288, 1048576);
    transpose_cvt<<<dim3(32, 16, 8), tb, 0, stream>>>(wr_down, wrd_t,               512, 1024, 524288, 524288);
    transpose_cvt<<<dim3(16, 32, 2), tb, 0, stream>>>(ws_gate, wsgu_t,              1024, 512, 524288, 1048576);
    transpose_cvt<<<dim3(16, 32, 2), tb, 0, stream>>>(ws_up,   wsgu_t + 512 * 1024, 1024, 512, 524288, 1048576);
    transpose_cvt<<<dim3(32, 16, 2), tb, 0, stream>>>(ws_down, wsd_t,               512, 1024, 524288, 524288);

    // MoE path (routed sparse + 2 shared), accumulating into d_out (= x_mid copy)
    zero_meta<<<1, 64, 0, stream>>>(meta);
    rmsnorm_kernel<<<T_, 256, 0, stream>>>(x_mid, mlp_nw, h2);
    gate_kernel<<<T_, 256, 0, stream>>>(x_mid, mlp_nw, gate_w, tok_e, tok_w, cnt);
    prefix_kernel<<<1, 64, 0, stream>>>(cnt, off, cursor);
    scatter_kernel<<<16, 256, 0, stream>>>(tok_e, tok_w, cursor, elist, ewgt);
    gemm_gather<<<dim3(8, 32, 8), 256, 0, stream>>>(h2, wrgu_t, gu_r, cnt, off, elist);
    silu_mul<<<(8192 * 512) / 256, 256, 0, stream>>>(gu_r, act_r, 8192);
    gemm_rdown<<<dim3(8, 32, 8), 256, 0, stream>>>(act_r, wrd_t, out, cnt, off, elist, ewgt);
    for (int e = 0; e < 2; ++e) {
        gemm_k<<<dim3(8, 32), 256, 0, stream>>>(h2, 1024, wsgu_t + (size_t)e * 1048576, gu_s, 1024, 1024, 1, nullptr, nullptr);
        silu_mul<<<(4096 * 512) / 256, 256, 0, stream>>>(gu_s, act_s, 4096);
        gemm_k<<<dim3(8, 32), 256, 0, stream>>>(act_s, 512, wsd_t + (size_t)e * 524288, out, 1024, 512, 2, nullptr, nullptr);
    }
}

// Round 7
// 766.528 us; speedup vs baseline: 20.6621x; 1.0824x over previous
//
#include <hip/hip_runtime.h>
#include <hip/hip_bf16.h>
#include <stdint.h>

typedef unsigned short u16;
typedef __attribute__((ext_vector_type(8))) short short8;
typedef __attribute__((ext_vector_type(4))) float f32x4;
typedef __attribute__((ext_vector_type(2))) unsigned int u32x2;

#define B_    2
#define S_    2048
#define D_    1024
#define H_    16
#define T_    (B_*S_)

static __device__ __forceinline__ float b2f(u16 h) { return __uint_as_float(((uint32_t)h) << 16); }
static __device__ __forceinline__ u16 f2b(float f) {
    uint32_t u = __float_as_uint(f);
    u += 0x7fffu + ((u >> 16) & 1u);          // RNE
    return (u16)(u >> 16);
}
static __device__ __forceinline__ uint32_t pack2(float a, float b) {
    return (uint32_t)f2b(a) | ((uint32_t)f2b(b) << 16);
}
#define MFMA(a,b,c) __builtin_amdgcn_mfma_f32_16x16x32_bf16(a,b,c,0,0,0)

// async global->LDS, 16B per lane; lds dest = wave-uniform base + lane*16B
static __device__ __forceinline__ void gl2lds16(const void* g, void* l) {
    __builtin_amdgcn_global_load_lds((const __attribute__((address_space(1))) void*)g,
                                     (__attribute__((address_space(3))) void*)l, 16, 0, 0);
}

// ---------------- transpose + f32->bf16 convert: out[n][k] = in[k][n] ----------------
__global__ __launch_bounds__(256) void transpose_cvt(const float* __restrict__ in,
    u16* __restrict__ out, int K, int N, long inEZ, long outEZ)
{
    __shared__ float tile[32][33];
    const int e = blockIdx.z;
    const float* ip = in + (long)e * inEZ;
    u16* op = out + (long)e * outEZ;
    int n0 = blockIdx.x * 32, k0 = blockIdx.y * 32;
    int tx = threadIdx.x, ty = threadIdx.y;   // 32 x 8
#pragma unroll
    for (int i = 0; i < 4; ++i) {
        int k = k0 + ty + 8 * i, n = n0 + tx;
        tile[ty + 8 * i][tx] = (k < K && n < N) ? ip[(long)k * N + n] : 0.f;
    }
    __syncthreads();
#pragma unroll
    for (int i = 0; i < 4; ++i) {
        int n = n0 + ty + 8 * i, k = k0 + tx;
        if (n < N && k < K) op[(long)n * K + k] = f2b(tile[tx][ty + 8 * i]);
    }
}

// ---------------- MFMA GEMM: C = A(lda) * Bt(ldb)^T; all dims %128==0 ----------------
// mode: 1 = bf16 store, 2 = f32 +=, 3 = f32 store of (v + resid)
__global__ __launch_bounds__(256) void gemm_k(const u16* __restrict__ A, long lda,
    const u16* __restrict__ Bt, long ldb, void* __restrict__ Cv, long ldc, int K,
    int mode, const float* __restrict__ resid)
{
    __shared__ u16 As[128 * 32];
    __shared__ u16 Bs[128 * 32];
    const int tid = threadIdx.x, lane = tid & 63, wave = tid >> 6;
    const int wm = (wave & 1) * 64, wn = (wave >> 1) * 64;
    const int quad = lane >> 4, rr = lane & 15, q8 = quad * 8;
    const long row0 = (long)blockIdx.y * 128, col0 = (long)blockIdx.x * 128;
    f32x4 acc[4][4];
#pragma unroll
    for (int i = 0; i < 4; ++i)
#pragma unroll
        for (int j = 0; j < 4; ++j)
#pragma unroll
            for (int c = 0; c < 4; ++c) acc[i][j][c] = 0.f;
    const int band = wave * 32;
    const u16* ga = A + (row0 + band + (lane >> 2)) * lda + (lane & 3) * 8;
    const u16* gb = Bt + (col0 + band + (lane >> 2)) * ldb + (lane & 3) * 8;
    u16* la = &As[band * 32];
    u16* lb = &Bs[band * 32];
    for (int k0 = 0; k0 < K; k0 += 32) {
        gl2lds16(ga + k0, la);
        gl2lds16(ga + k0 + 16 * lda, la + 16 * 32);
        gl2lds16(gb + k0, lb);
        gl2lds16(gb + k0 + 16 * ldb, lb + 16 * 32);
        __syncthreads();
        short8 af[4], bf[4];
#pragma unroll
        for (int mi = 0; mi < 4; ++mi) af[mi] = *(const short8*)&As[(wm + mi * 16 + rr) * 32 + q8];
#pragma unroll
        for (int ni = 0; ni < 4; ++ni) bf[ni] = *(const short8*)&Bs[(wn + ni * 16 + rr) * 32 + q8];
#pragma unroll
        for (int mi = 0; mi < 4; ++mi)
#pragma unroll
            for (int ni = 0; ni < 4; ++ni)
                acc[mi][ni] = MFMA(af[mi], bf[ni], acc[mi][ni]);
        __syncthreads();
    }
#pragma unroll
    for (int mi = 0; mi < 4; ++mi)
#pragma unroll
        for (int ni = 0; ni < 4; ++ni)
#pragma unroll
            for (int rg = 0; rg < 4; ++rg) {
                long r = row0 + wm + mi * 16 + quad * 4 + rg;
                long c = col0 + wn + ni * 16 + rr;
                float v = acc[mi][ni][rg];
                if (mode == 1)      ((u16*)Cv)[r * ldc + c] = f2b(v);
                else if (mode == 2) ((float*)Cv)[r * ldc + c] += v;
                else                ((float*)Cv)[r * ldc + c] = v + resid[r * 1024 + c];
            }
}

// ---------------- gathered-row GEMM, routed gate|up (N=1024/expert) ----------------
__global__ __launch_bounds__(256) void gemm_gather(const u16* __restrict__ H2,
    const u16* __restrict__ BtAll, u16* __restrict__ C,
    const int* __restrict__ cnt, const int* __restrict__ off,
    const int* __restrict__ elist)
{
    const int e = blockIdx.z;
    const int cntE = cnt[e], offE = off[e];
    const int m0 = blockIdx.y * 128;
    if (m0 >= cntE) return;
    const u16* Bt = BtAll + (long)e * 1024 * 1024;
    __shared__ u16 As[128 * 32];
    __shared__ u16 Bs[128 * 32];
    const int tid = threadIdx.x, lane = tid & 63, wave = tid >> 6;
    const int wm = (wave & 1) * 64, wn = (wave >> 1) * 64;
    const int quad = lane >> 4, rr = lane & 15, q8 = quad * 8;
    const long col0 = (long)blockIdx.x * 128;
    f32x4 acc[4][4];
#pragma unroll
    for (int i = 0; i < 4; ++i)
#pragma unroll
        for (int j = 0; j < 4; ++j)
#pragma unroll
            for (int c = 0; c < 4; ++c) acc[i][j][c] = 0.f;
    const int band = wave * 32;
    int r0 = m0 + band + (lane >> 2);
    int r1 = r0 + 16;
    int tok0 = elist[offE + (r0 < cntE ? r0 : cntE - 1)];
    int tok1 = elist[offE + (r1 < cntE ? r1 : cntE - 1)];
    const u16* ga0 = H2 + (long)tok0 * 1024 + (lane & 3) * 8;
    const u16* ga1 = H2 + (long)tok1 * 1024 + (lane & 3) * 8;
    const u16* gb = Bt + (col0 + band + (lane >> 2)) * 1024L + (lane & 3) * 8;
    u16* la = &As[band * 32];
    u16* lb = &Bs[band * 32];
    for (int k0 = 0; k0 < 1024; k0 += 32) {
        gl2lds16(ga0 + k0, la);
        gl2lds16(ga1 + k0, la + 16 * 32);
        gl2lds16(gb + k0, lb);
        gl2lds16(gb + k0 + 16 * 1024, lb + 16 * 32);
        __syncthreads();
        short8 af[4], bf[4];
#pragma unroll
        for (int mi = 0; mi < 4; ++mi) af[mi] = *(const short8*)&As[(wm + mi * 16 + rr) * 32 + q8];
#pragma unroll
        for (int ni = 0; ni < 4; ++ni) bf[ni] = *(const short8*)&Bs[(wn + ni * 16 + rr) * 32 + q8];
#pragma unroll
        for (int mi = 0; mi < 4; ++mi)
#pragma unroll
            for (int ni = 0; ni < 4; ++ni)
                acc[mi][ni] = MFMA(af[mi], bf[ni], acc[mi][ni]);
        __syncthreads();
    }
#pragma unroll
    for (int mi = 0; mi < 4; ++mi)
#pragma unroll
        for (int ni = 0; ni < 4; ++ni)
#pragma unroll
            for (int rg = 0; rg < 4; ++rg) {
                int ml = wm + mi * 16 + quad * 4 + rg;
                long c = col0 + wn + ni * 16 + rr;
                if (m0 + ml < cntE)
                    C[(long)(offE + m0 + ml) * 1024 + c] = f2b(acc[mi][ni][rg]);
            }
}

// ---------------- routed down GEMM: rout[slot] = act[slot] * wd[e]^T (bf16) ----------------
__global__ __launch_bounds__(256) void gemm_slot(const u16* __restrict__ Act,
    const u16* __restrict__ BtAll, u16* __restrict__ rout,
    const int* __restrict__ cnt, const int* __restrict__ off)
{
    const int e = blockIdx.z;
    const int cntE = cnt[e], offE = off[e];
    const int m0 = blockIdx.y * 128;
    if (m0 >= cntE) return;
    const u16* Bt = BtAll + (long)e * 1024 * 512;
    __shared__ u16 As[128 * 32];
    __shared__ u16 Bs[128 * 32];
    const int tid = threadIdx.x, lane = tid & 63, wave = tid >> 6;
    const int wm = (wave & 1) * 64, wn = (wave >> 1) * 64;
    const int quad = lane >> 4, rr = lane & 15, q8 = quad * 8;
    const long col0 = (long)blockIdx.x * 128;
    f32x4 acc[4][4];
#pragma unroll
    for (int i = 0; i < 4; ++i)
#pragma unroll
        for (int j = 0; j < 4; ++j)
#pragma unroll
            for (int c = 0; c < 4; ++c) acc[i][j][c] = 0.f;
    const int band = wave * 32;
    int r0 = offE + m0 + band + (lane >> 2); if (r0 > 8191) r0 = 8191;
    int r1 = r0 + 16; if (r1 > 8191) r1 = 8191;
    const u16* ga0 = Act + (long)r0 * 1024 + (lane & 3) * 8;   // act in gate half, lda=1024
    const u16* ga1 = Act + (long)r1 * 1024 + (lane & 3) * 8;
    const u16* gb = Bt + (col0 + band + (lane >> 2)) * 512L + (lane & 3) * 8;
    u16* la = &As[band * 32];
    u16* lb = &Bs[band * 32];
    for (int k0 = 0; k0 < 512; k0 += 32) {
        gl2lds16(ga0 + k0, la);
        gl2lds16(ga1 + k0, la + 16 * 32);
        gl2lds16(gb + k0, lb);
        gl2lds16(gb + k0 + 16 * 512, lb + 16 * 32);
        __syncthreads();
        short8 af[4], bf[4];
#pragma unroll
        for (int mi = 0; mi < 4; ++mi) af[mi] = *(const short8*)&As[(wm + mi * 16 + rr) * 32 + q8];
#pragma unroll
        for (int ni = 0; ni < 4; ++ni) bf[ni] = *(const short8*)&Bs[(wn + ni * 16 + rr) * 32 + q8];
#pragma unroll
        for (int mi = 0; mi < 4; ++mi)
#pragma unroll
            for (int ni = 0; ni < 4; ++ni)
                acc[mi][ni] = MFMA(af[mi], bf[ni], acc[mi][ni]);
        __syncthreads();
    }
#pragma unroll
    for (int mi = 0; mi < 4; ++mi)
#pragma unroll
        for (int ni = 0; ni < 4; ++ni)
#pragma unroll
            for (int rg = 0; rg < 4; ++rg) {
                int ml = wm + mi * 16 + quad * 4 + rg;
                long c = col0 + wn + ni * 16 + rr;
                if (m0 + ml < cntE)
                    rout[(long)(offE + m0 + ml) * 1024 + c] = f2b(acc[mi][ni][rg]);
            }
}

// ---------------- rmsnorm f32 -> bf16 ----------------
__global__ __launch_bounds__(256) void rmsnorm_kernel(const float* __restrict__ x,
    const float* __restrict__ w, u16* __restrict__ out)
{
    int t = blockIdx.x, tid = threadIdx.x;
    const float* xp = x + (size_t)t * D_;
    __shared__ float red[256];
    float s = 0.f;
    for (int d = tid; d < D_; d += 256) { float v = xp[d]; s += v * v; }
    red[tid] = s; __syncthreads();
    for (int o = 128; o > 0; o >>= 1) { if (tid < o) red[tid] += red[tid + o]; __syncthreads(); }
    float inv = rsqrtf(red[0] * (1.f / D_) + 1e-6f);
    u16* op = out + (size_t)t * D_;
    for (int d = tid; d < D_; d += 256) op[d] = f2b(xp[d] * inv * w[d]);
}

// ---------------- RoPE on q (proj cols h*128+64..h*128+127, stride 2688) ----------------
__global__ __launch_bounds__(256) void rope_q_kernel(u16* __restrict__ proj)
{
    int idx = blockIdx.x * 256 + threadIdx.x;     // T_*H_*32
    int i  = idx & 31;
    int hh = (idx >> 5) & (H_ - 1);
    int t  = idx >> 9;
    int s  = t & (S_ - 1);
    float inv = __expf(-(float)i * 0.28782313662425575f);  // ln(10000)/32
    float ang = (float)s * inv;
    float c = cosf(ang), sn = sinf(ang);
    u16* base = proj + (size_t)t * 2688 + hh * 128 + 64;
    float t1 = b2f(base[i]), t2 = b2f(base[32 + i]);
    base[i]      = f2b(t1 * c - t2 * sn);
    base[32 + i] = f2b(t2 * c + t1 * sn);
}

// ---------------- RoPE on k_r (proj cols 2560..2623) ----------------
__global__ __launch_bounds__(256) void rope_kr_kernel(u16* __restrict__ proj)
{
    int idx = blockIdx.x * 256 + threadIdx.x;     // T_*32
    int i = idx & 31;
    int t = idx >> 5;
    int s = t & (S_ - 1);
    float inv = __expf(-(float)i * 0.28782313662425575f);
    float ang = (float)s * inv;
    float c = cosf(ang), sn = sinf(ang);
    u16* base = proj + (size_t)t * 2688 + 2560;
    float t1 = b2f(base[i]), t2 = b2f(base[32 + i]);
    base[i]      = f2b(t1 * c - t2 * sn);
    base[32 + i] = f2b(t2 * c + t1 * sn);
}

// ---------------- flash attention, transposed-S formulation ----------------
// BQ=128 x BK=64. S^T = K·Q^T (lane owns one q-row -> scalar m/l, b64 P stores);
// O^T = V^T·P^T with V^T pre-transposed in global (vt[1024][4096]).
#define KS  136
#define VS2 72
#define PS2 72
__global__ __launch_bounds__(256) void attn_flash(const u16* __restrict__ proj,
    const u16* __restrict__ kc, const u16* __restrict__ vt, u16* __restrict__ ctx)
{
    const int qidx = blockIdx.x >> 5;
    const int qt = (qidx < 8) ? (15 - qidx) : (qidx - 8);
    const int bh = blockIdx.x & 31;
    const int b = bh >> 4, h = bh & 15;
    const int q0 = qt * 128;
    const int tid = threadIdx.x, lane = tid & 63, wave = tid >> 6;
    const int quad = lane >> 4, rr = lane & 15, q8 = quad * 8;
    const int wm2 = wave * 32;

    __shared__ u16 Ks[64 * KS];    // [key][d0..127]
    __shared__ u16 Vs[64 * VS2];   // [vd][key]
    __shared__ u16 Ps[128 * PS2];  // [qrow][key]

    const long tbase = (long)b * S_ + q0;
    short8 qf[2][4];
#pragma unroll
    for (int mi = 0; mi < 2; ++mi)
#pragma unroll
        for (int d0 = 0; d0 < 4; ++d0)
            qf[mi][d0] = *(const short8*)&proj[(tbase + wm2 + mi * 16 + rr) * 2688 + h * 128 + d0 * 32 + q8];

    f32x4 accO[2][4];              // O^T: [mi][vi], lane: vd=vi*16+quad*4+rg, qrow=rr
    float m_i[2], l_i[2];
#pragma unroll
    for (int mi = 0; mi < 2; ++mi) {
#pragma unroll
        for (int vi = 0; vi < 4; ++vi)
#pragma unroll
            for (int rg = 0; rg < 4; ++rg) accO[mi][vi][rg] = 0.f;
        m_i[mi] = -3e38f; l_i[mi] = 0.f;
    }
    const float sc = 0.08838834764831845f * 1.4426950408889634f;

    const int nkt = 2 * qt + 2;
    for (int kt = 0; kt < nkt; ++kt) {
        const int k0 = kt * 64;
        const long kb = (long)b * S_ + k0;
        // stage K rows (cols 0..63 from kc, 64..127 from proj kr)
#pragma unroll
        for (int i = 0; i < 2; ++i) {
            int c = tid + i * 256, row = c >> 3, cc = (c & 7) * 8;
            *(short8*)&Ks[row * KS + cc] = *(const short8*)&kc[(kb + row) * 1024 + h * 64 + cc];
        }
#pragma unroll
        for (int i = 0; i < 2; ++i) {
            int c = tid + i * 256, row = c >> 3, cc = (c & 7) * 8;
            *(short8*)&Ks[row * KS + 64 + cc] = *(const short8*)&proj[(kb + row) * 2688 + 2560 + cc];
        }
        // stage V^T rows (vd x 64 keys), fully vectorized
#pragma unroll
        for (int i = 0; i < 2; ++i) {
            int c = tid + i * 256, row = c >> 3, cc = (c & 7) * 8;
            *(short8*)&Vs[row * VS2 + cc] =
                *(const short8*)&vt[(long)(h * 64 + row) * 4096 + b * 2048 + k0 + cc];
        }
        __syncthreads();

        const bool act0 = (k0 <= q0 + wm2 + 15);
        const bool act1 = (k0 <= q0 + wm2 + 31);
        f32x4 accS[2][4];          // S^T: [mi][ki], lane: key=ki*16+quad*4+rg, qrow=rr
#pragma unroll
        for (int mi = 0; mi < 2; ++mi)
#pragma unroll
            for (int ki = 0; ki < 4; ++ki)
#pragma unroll
                for (int rg = 0; rg < 4; ++rg) accS[mi][ki][rg] = 0.f;
#pragma unroll
        for (int d0 = 0; d0 < 4; ++d0) {
            short8 kf[4];
#pragma unroll
            for (int ki = 0; ki < 4; ++ki) kf[ki] = *(const short8*)&Ks[(ki * 16 + rr) * KS + d0 * 32 + q8];
            if (act0) {
#pragma unroll
                for (int ki = 0; ki < 4; ++ki) accS[0][ki] = MFMA(kf[ki], qf[0][d0], accS[0][ki]);
            }
            if (act1) {
#pragma unroll
                for (int ki = 0; ki < 4; ++ki) accS[1][ki] = MFMA(kf[ki], qf[1][d0], accS[1][ki]);
            }
        }
#pragma unroll
        for (int mi = 0; mi < 2; ++mi) {
            if (!(mi ? act1 : act0)) continue;
            const int qg = q0 + wm2 + mi * 16 + rr;
            const bool maybe_mask = (k0 + 63 > q0 + wm2 + mi * 16);
            float mx = -3e38f;
#pragma unroll
            for (int ki = 0; ki < 4; ++ki)
#pragma unroll
                for (int rg = 0; rg < 4; ++rg) {
                    float w = accS[mi][ki][rg] * sc;
                    if (maybe_mask && (k0 + ki * 16 + quad * 4 + rg > qg)) w = -1e30f;
                    accS[mi][ki][rg] = w;
                    mx = fmaxf(mx, w);
                }
            mx = fmaxf(mx, __shfl_xor(mx, 16));
            mx = fmaxf(mx, __shfl_xor(mx, 32));
            float mnew = fmaxf(m_i[mi], mx);
            float alpha = exp2f(m_i[mi] - mnew);
            m_i[mi] = mnew;
            float ps = 0.f;
#pragma unroll
            for (int ki = 0; ki < 4; ++ki) {
                float p0 = exp2f(accS[mi][ki][0] - mnew);
                float p1 = exp2f(accS[mi][ki][1] - mnew);
                float p2 = exp2f(accS[mi][ki][2] - mnew);
                float p3 = exp2f(accS[mi][ki][3] - mnew);
                ps += (p0 + p1) + (p2 + p3);
                u32x2 pk; pk[0] = pack2(p0, p1); pk[1] = pack2(p2, p3);
                *(u32x2*)&Ps[(wm2 + mi * 16 + rr) * PS2 + ki * 16 + quad * 4] = pk;
            }
            ps += __shfl_xor(ps, 16);
            ps += __shfl_xor(ps, 32);
            l_i[mi] = l_i[mi] * alpha + ps;
#pragma unroll
            for (int vi = 0; vi < 4; ++vi)
#pragma unroll
                for (int rg = 0; rg < 4; ++rg) accO[mi][vi][rg] *= alpha;
        }
        // O^T += V^T · P^T
#pragma unroll
        for (int kc0 = 0; kc0 < 64; kc0 += 32) {
            short8 vf[4];
#pragma unroll
            for (int vi = 0; vi < 4; ++vi) vf[vi] = *(const short8*)&Vs[(vi * 16 + rr) * VS2 + kc0 + q8];
            if (act0) {
                short8 pf = *(const short8*)&Ps[(wm2 + rr) * PS2 + kc0 + q8];
#pragma unroll
                for (int vi = 0; vi < 4; ++vi) accO[0][vi] = MFMA(vf[vi], pf, accO[0][vi]);
            }
            if (act1) {
                short8 pf = *(const short8*)&Ps[(wm2 + 16 + rr) * PS2 + kc0 + q8];
#pragma unroll
                for (int vi = 0; vi < 4; ++vi) accO[1][vi] = MFMA(vf[vi], pf, accO[1][vi]);
            }
        }
        __syncthreads();
    }
    // epilogue: ctx[t][h*64+vd] = O^T/l, packed 8B stores
#pragma unroll
    for (int mi = 0; mi < 2; ++mi) {
        float linv = 1.f / l_i[mi];
        long t = tbase + wm2 + mi * 16 + rr;
#pragma unroll
        for (int vi = 0; vi < 4; ++vi) {
            u32x2 pk;
            pk[0] = pack2(accO[mi][vi][0] * linv, accO[mi][vi][1] * linv);
            pk[1] = pack2(accO[mi][vi][2] * linv, accO[mi][vi][3] * linv);
            *(u32x2*)&ctx[t * 1024 + h * 64 + vi * 16 + quad * 4] = pk;
        }
    }
}

// ---------------- zero meta ----------------
__global__ void zero_meta(int* __restrict__ m) { if (threadIdx.x < 24) m[threadIdx.x] = 0; }

// ---------------- gate: f32 rmsnorm + logits + top2 + counting ----------------
__global__ __launch_bounds__(256) void gate_kernel(const float* __restrict__ xm,
    const float* __restrict__ nw, const float* __restrict__ gw,
    int* __restrict__ tok_e, float* __restrict__ tok_w, int* __restrict__ cnt)
{
    int t = blockIdx.x, tid = threadIdx.x;
    const float* xp = xm + (size_t)t * D_;
    __shared__ float red[256];
    float s = 0.f;
    for (int d = tid; d < D_; d += 256) { float v = xp[d]; s += v * v; }
    red[tid] = s; __syncthreads();
    for (int o = 128; o > 0; o >>= 1) { if (tid < o) red[tid] += red[tid + o]; __syncthreads(); }
    float inv = rsqrtf(red[0] * (1.f / D_) + 1e-6f);
    __syncthreads();
    float part[8] = {0,0,0,0,0,0,0,0};
    for (int d = tid; d < D_; d += 256) {
        float hv = xp[d] * inv * nw[d];
#pragma unroll
        for (int e = 0; e < 8; ++e) part[e] += hv * gw[d * 8 + e];
    }
    __shared__ float logits[8];
    for (int e = 0; e < 8; ++e) {
        red[tid] = part[e]; __syncthreads();
        for (int o = 128; o > 0; o >>= 1) { if (tid < o) red[tid] += red[tid + o]; __syncthreads(); }
        if (tid == 0) logits[e] = red[0];
        __syncthreads();
    }
    if (tid == 0) {
        float mx = logits[0];
        for (int e = 1; e < 8; ++e) mx = fmaxf(mx, logits[e]);
        float p[8], ps = 0.f;
        for (int e = 0; e < 8; ++e) { p[e] = __expf(logits[e] - mx); ps += p[e]; }
        for (int e = 0; e < 8; ++e) p[e] /= ps;
        int i0 = 0;
        for (int e = 1; e < 8; ++e) if (p[e] > p[i0]) i0 = e;
        int i1 = (i0 == 0) ? 1 : 0;
        for (int e = 0; e < 8; ++e) { if (e == i0) continue; if (p[e] > p[i1]) i1 = e; }
        float sw = p[i0] + p[i1];
        tok_e[2 * t] = i0;  tok_e[2 * t + 1] = i1;
        tok_w[2 * t] = p[i0] / sw;  tok_w[2 * t + 1] = p[i1] / sw;
        atomicAdd(&cnt[i0], 1);
        atomicAdd(&cnt[i1], 1);
    }
}

__global__ void prefix_kernel(const int* __restrict__ cnt, int* __restrict__ off,
    int* __restrict__ cursor)
{
    if (threadIdx.x == 0 && blockIdx.x == 0) {
        int s = 0;
        for (int e = 0; e < 8; ++e) { off[e] = s; cursor[e] = s; s += cnt[e]; }
    }
}

__global__ __launch_bounds__(256) void scatter_kernel(const int* __restrict__ tok_e,
    int* __restrict__ cursor, int* __restrict__ elist, int* __restrict__ tok_slot)
{
    int t = blockIdx.x * 256 + threadIdx.x;
    if (t >= T_) return;
    for (int j = 0; j < 2; ++j) {
        int e = tok_e[2 * t + j];
        int slot = atomicAdd(&cursor[e], 1);
        elist[slot] = t;
        tok_slot[2 * t + j] = slot;
    }
}

// ---------------- silu in-place: gu[row][j] = silu(gu[row][j]) * gu[row][512+j] ----------------
__global__ __launch_bounds__(256) void silu_mul(u16* __restrict__ gu, int nPairRows)
{
    int i = blockIdx.x * 256 + threadIdx.x;
    if (i >= nPairRows * 512) return;
    int row = i >> 9, j = i & 511;
    long base = (long)row * 1024;
    float g = b2f(gu[base + j]), u = b2f(gu[base + 512 + j]);
    gu[base + j] = f2b(g / (1.f + __expf(-g)) * u);
}

// ---------------- final: out = x_mid + w0*rout[s0] + w1*rout[s1] ----------------
__global__ __launch_bounds__(256) void final_kernel(const float* __restrict__ xm,
    const u16* __restrict__ rout, const int* __restrict__ tok_slot,
    const float* __restrict__ tok_w, float* __restrict__ out)
{
    long i = (long)blockIdx.x * 256 + threadIdx.x;
    int t = (int)(i >> 10), d = (int)(i & 1023);
    int s0 = tok_slot[2 * t], s1 = tok_slot[2 * t + 1];
    float w0 = tok_w[2 * t], w1 = tok_w[2 * t + 1];
    out[i] = xm[i] + w0 * b2f(rout[(long)s0 * 1024 + d]) + w1 * b2f(rout[(long)s1 * 1024 + d]);
}

// ---------------- workspace layout (bytes); peak ~108.2 MB ----------------
// (no trailing backslashes in comments -- that swallowed OFF_GUR last round)
#define OFF_XMID   0UL            // f32 4096x1024 (16.78M), lives whole call
#define OFF_H      16777216UL     // h -> h2, bf16 4096x1024 (8.39M)
#define OFF_PROJ   25165824UL     // proj 4096x2688 (22.02M); phase2: wgu_t 10x1Mx2B
#define OFF_WGU    25165824UL
#define OFF_KC     47185920UL     // kc 4096x1024 (8.39M); phase2: wd_t 10x0.5Mx2B
#define OFF_WD     47185920UL
#define OFF_VT     55574528UL     // vt 1024x4096 (8.39M), dead after attn
#define OFF_GUR    57671680UL     // gu_r 8192x1024 (16.78M), overlays vt tail + ctx
#define OFF_CTX    63963136UL     // ctx 4096x1024 (8.39M)
#define OFF_WATT   72351744UL     // wqkv 5.51M, wuk 1.05M, wuv 1.05M, wo 2.10M
#define OFF_ROUT   74448896UL     // rout 8192x1024 bf16 (16.78M), overlays attn weights
#define OFF_GUS    91226112UL     // gu_s 4096x2048 bf16 (16.78M)
#define OFF_TOKE   108003328UL
#define OFF_TOKW   108036096UL
#define OFF_TSLOT  108068864UL
#define OFF_ELIST  108101632UL
#define OFF_META   108134400UL

extern "C" void kernel_launch(void* const* d_in, const int* in_sizes, int n_in,
                              void* d_out, int out_size, void* d_ws, size_t ws_size,
                              hipStream_t stream)
{
    const float* x       = (const float*)d_in[0];
    const float* w_q     = (const float*)d_in[2];
    const float* w_dkv   = (const float*)d_in[3];
    const float* w_uk    = (const float*)d_in[4];
    const float* w_uv    = (const float*)d_in[5];
    const float* w_kr    = (const float*)d_in[6];
    const float* w_o     = (const float*)d_in[7];
    const float* attn_nw = (const float*)d_in[8];
    const float* mlp_nw  = (const float*)d_in[9];
    const float* gate_w  = (const float*)d_in[10];
    const float* wr_gate = (const float*)d_in[11];
    const float* wr_up   = (const float*)d_in[12];
    const float* wr_down = (const float*)d_in[13];
    const float* ws_gate = (const float*)d_in[14];
    const float* ws_up   = (const float*)d_in[15];
    const float* ws_down = (const float*)d_in[16];
    float* out = (float*)d_out;

    char* W = (char*)d_ws;
    float* x_mid = (float*)(W + OFF_XMID);
    u16* h      = (u16*)(W + OFF_H);
    u16* h2     = (u16*)(W + OFF_H);
    u16* proj   = (u16*)(W + OFF_PROJ);
    u16* wgu_t  = (u16*)(W + OFF_WGU);
    u16* kc     = (u16*)(W + OFF_KC);
    u16* wd_t   = (u16*)(W + OFF_WD);
    u16* vt     = (u16*)(W + OFF_VT);
    u16* gu_r   = (u16*)(W + OFF_GUR);
    u16* ctx    = (u16*)(W + OFF_CTX);
    u16* wqkv_t = (u16*)(W + OFF_WATT);
    u16* wuk_t  = wqkv_t + 2688 * 1024;
    u16* wuv_t  = wuk_t + 1024 * 512;
    u16* wo_t   = wuv_t + 1024 * 512;
    u16* rout   = (u16*)(W + OFF_ROUT);
    u16* gu_s   = (u16*)(W + OFF_GUS);
    int*   tok_e = (int*)(W + OFF_TOKE);
    float* tok_w = (float*)(W + OFF_TOKW);
    int*   tslot = (int*)(W + OFF_TSLOT);
    int*   elist = (int*)(W + OFF_ELIST);
    int*   meta  = (int*)(W + OFF_META);
    int* cnt = meta, * off = meta + 8, * cursor = meta + 16;

    dim3 tb(32, 8);
    // attn weights (packed qkv rows: 0..2047 q | 2048..2559 dkv | 2560..2623 kr | 2624..2687 junk)
    transpose_cvt<<<dim3(64, 32, 1), tb, 0, stream>>>(w_q,   wqkv_t,               1024, 2048, 0, 0);
    transpose_cvt<<<dim3(16, 32, 1), tb, 0, stream>>>(w_dkv, wqkv_t + 2048 * 1024, 1024, 512,  0, 0);
    transpose_cvt<<<dim3(2,  32, 1), tb, 0, stream>>>(w_kr,  wqkv_t + 2560 * 1024, 1024, 64,   0, 0);
    transpose_cvt<<<dim3(32, 16, 1), tb, 0, stream>>>(w_uk,  wuk_t,                512,  1024, 0, 0);
    transpose_cvt<<<dim3(32, 16, 1), tb, 0, stream>>>(w_uv,  wuv_t,                512,  1024, 0, 0);
    transpose_cvt<<<dim3(32, 32, 1), tb, 0, stream>>>(w_o,   wo_t,                 1024, 1024, 0, 0);

    // attention path
    rmsnorm_kernel<<<T_, 256, 0, stream>>>(x, attn_nw, h);
    gemm_k<<<dim3(21, 32), 256, 0, stream>>>(h, 1024, wqkv_t, 1024, proj, 2688, 1024, 1, nullptr);
    rope_q_kernel<<<(T_ * H_ * 32) / 256, 256, 0, stream>>>(proj);
    rope_kr_kernel<<<(T_ * 32) / 256, 256, 0, stream>>>(proj);
    gemm_k<<<dim3(8, 32), 256, 0, stream>>>(proj + 2048, 2688, wuk_t, 512, kc, 1024, 512, 1, nullptr);
    gemm_k<<<dim3(32, 8), 256, 0, stream>>>(wuv_t, 512, proj + 2048, 2688, vt, 4096, 512, 1, nullptr);  // V^T
    attn_flash<<<512, 256, 0, stream>>>(proj, kc, vt, ctx);
    gemm_k<<<dim3(8, 32), 256, 0, stream>>>(ctx, 1024, wo_t, 1024, x_mid, 1024, 1024, 3, x);

    // MoE weights (after attn: overlay proj/kc; experts 0..7 routed, 8..9 shared)
    transpose_cvt<<<dim3(16, 32, 8), tb, 0, stream>>>(wr_gate, wgu_t,              1024, 512, 524288, 1048576);
    transpose_cvt<<<dim3(16, 32, 8), tb, 0, stream>>>(wr_up,   wgu_t + 512 * 1024, 1024, 512, 524288, 1048576);
    transpose_cvt<<<dim3(16, 32, 2), tb, 0, stream>>>(ws_gate, wgu_t + 8 * 1048576,              1024, 512, 524288, 1048576);
    transpose_cvt<<<dim3(16, 32, 2), tb, 0, stream>>>(ws_up,   wgu_t + 8 * 1048576 + 512 * 1024, 1024, 512, 524288, 1048576);
    transpose_cvt<<<dim3(32, 16, 8), tb, 0, stream>>>(wr_down, wd_t,               512, 1024, 524288, 524288);
    transpose_cvt<<<dim3(32, 16, 2), tb, 0, stream>>>(ws_down, wd_t + 8 * 524288,  512, 1024, 524288, 524288);

    // MoE path
    zero_meta<<<1, 64, 0, stream>>>(meta);
    rmsnorm_kernel<<<T_, 256, 0, stream>>>(x_mid, mlp_nw, h2);
    gate_kernel<<<T_, 256, 0, stream>>>(x_mid, mlp_nw, gate_w, tok_e, tok_w, cnt);
    prefix_kernel<<<1, 64, 0, stream>>>(cnt, off, cursor);
    scatter_kernel<<<16, 256, 0, stream>>>(tok_e, cursor, elist, tslot);
    // routed: gather gate|up -> silu in place -> down -> rout (no atomics)
    gemm_gather<<<dim3(8, 64, 8), 256, 0, stream>>>(h2, wgu_t, gu_r, cnt, off, elist);
    silu_mul<<<(8192 * 512) / 256, 256, 0, stream>>>(gu_r, 8192);
    gemm_slot<<<dim3(8, 64, 8), 256, 0, stream>>>(gu_r, wd_t, rout, cnt, off);
    // shared: one N=2048 gate|up GEMM, silu in place, two downs += x_mid
    gemm_k<<<dim3(16, 32), 256, 0, stream>>>(h2, 1024, wgu_t + 8 * 1048576, 1024, gu_s, 2048, 1024, 1, nullptr);
    silu_mul<<<(8192 * 512) / 256, 256, 0, stream>>>(gu_s, 8192);
    gemm_k<<<dim3(8, 32), 256, 0, stream>>>(gu_s, 2048, wd_t + 8 * 524288, 512, x_mid, 1024, 512, 2, nullptr);
    gemm_k<<<dim3(8, 32), 256, 0, stream>>>(gu_s + 1024, 2048, wd_t + 9 * 524288, 512, x_mid, 1024, 512, 2, nullptr);
    final_kernel<<<(T_ * D_) / 256, 256, 0, stream>>>(x_mid, rout, tslot, tok_w, out);
}